// Round 2
// baseline (304.053 us; speedup 1.0000x reference)
//
#include <hip/hip_runtime.h>
#include <hip/hip_bf16.h>
#include <stdint.h>

// Problem constants
#define B_   2
#define H_   96
#define W_   96
#define C_   96
#define HW_  (H_ * W_)       // 9216
#define NT_  (B_ * HW_)      // 18432
#define EPS_ 1e-5f
#define KSPLIT  8
#define KRANGE  (HW_ / KSPLIT)   // 1152 keys per block
#define ATT_NIT (KRANGE / 32)    // 36 iterations
// softmax scale with log2(e) folded in so native exp2 (v_exp_f32) works
#define SCL (0.10206207261596575f * 1.4426950408889634f)

typedef __hip_bfloat16 bf16;
typedef __attribute__((ext_vector_type(8))) short short8;   // 8 bf16 (MFMA A/B frag)
typedef __attribute__((ext_vector_type(16))) float f32x16;  // MFMA C/D frag

// Fast bf16x2 pack: round-half-up (+0x8000) then v_perm picks the two high
// halves. low16 = bf16(a), high16 = bf16(b).
__device__ __forceinline__ uint32_t pk_bf16(float a, float b) {
    uint32_t ua = __float_as_uint(a) + 0x8000u;
    uint32_t ub = __float_as_uint(b) + 0x8000u;
    return __builtin_amdgcn_perm(ub, ua, 0x07060302u);
}
__device__ __forceinline__ float bl(uint32_t u) { uint32_t x = u << 16;         return *(float*)&x; }
__device__ __forceinline__ float bh(uint32_t u) { uint32_t x = u & 0xffff0000u; return *(float*)&x; }
// raw v_exp_f32 (2-ulp; inputs bounded, result feeds bf16 -> plenty accurate)
__device__ __forceinline__ float fexp2(float x) { return __builtin_amdgcn_exp2f(x); }
// 16B LDS fragment read as 2x ds_read_b64 (8B-aligned; padded strides keep
// bank aliasing at 2-way which is free on gfx950)
__device__ __forceinline__ short8 lds_frag(const short* p) {
    union { int2 h[2]; short8 v; } t;
    t.h[0] = *(const int2*)(p);
    t.h[1] = *(const int2*)(p + 4);
    return t.v;
}

// Rebuild one lane's 48-channel GroupNorm'd fragment set from x + stats.
__device__ __forceinline__ void load_hn_frags(
        const float* __restrict__ x, const float2* __restrict__ stats,
        const float* __restrict__ gamma, const float* __restrict__ beta,
        int token, int hh, short8* hf) {
    int b = token / HW_;
    int h = (token % HW_) / W_;
    float2 st = stats[b * 32 + h / 3];
    float g0 = gamma[h];
    float ga = g0 * st.y;
    float be = beta[h] - st.x * st.y * g0;
    const float* xr = x + (size_t)token * C_ + hh * 8;
    #pragma unroll
    for (int s = 0; s < 6; ++s) {
        float4 a = *(const float4*)(xr + s * 16);
        float4 c = *(const float4*)(xr + s * 16 + 4);
        union { uint32_t w[4]; short8 v; } f;
        f.w[0] = pk_bf16(a.x * ga + be, a.y * ga + be);
        f.w[1] = pk_bf16(a.z * ga + be, a.w * ga + be);
        f.w[2] = pk_bf16(c.x * ga + be, c.y * ga + be);
        f.w[3] = pk_bf16(c.z * ga + be, c.w * ga + be);
        hf[s] = f.v;
    }
}

// ---------------------------------------------------------------------------
// Kernel 1: GroupNorm stats (blocks 0..63, float4 scan + shuffle reduce)
//           + weight transpose (blocks 64..67)
// ---------------------------------------------------------------------------
__global__ __launch_bounds__(1024)
void stats_prep_kernel(const float* __restrict__ x, float2* __restrict__ stats,
                       const float* __restrict__ Wq, const float* __restrict__ Wk,
                       const float* __restrict__ Wv, const float* __restrict__ Wp,
                       bf16* __restrict__ wqt, bf16* __restrict__ wkt,
                       bf16* __restrict__ wvt, bf16* __restrict__ wpt) {
    int blk = blockIdx.x;
    int tid = threadIdx.x;
    if (blk >= 64) {
        int wsel = blk - 64;
        const float* S = (wsel == 0) ? Wq : (wsel == 1) ? Wk : (wsel == 2) ? Wv : Wp;
        bf16* D = (wsel == 0) ? wqt : (wsel == 1) ? wkt : (wsel == 2) ? wvt : wpt;
        for (int i = tid; i < C_ * C_; i += 1024) {
            int r = i / C_, c = i % C_;
            D[c * C_ + r] = __float2bfloat16(S[r * C_ + c]);
        }
        return;
    }
    int b = blk >> 5, g = blk & 31;
    const int n4 = 3 * W_ * C_ / 4;   // 6912 float4s
    const float4* xb = (const float4*)(x + (size_t)(b * H_ + 3 * g) * (W_ * C_));
    float s = 0.f, ss = 0.f;
    for (int i = tid; i < n4; i += 1024) {
        float4 v = xb[i];
        s  += v.x + v.y + v.z + v.w;
        ss += v.x * v.x + v.y * v.y + v.z * v.z + v.w * v.w;
    }
    // wave shuffle reduce
    #pragma unroll
    for (int off = 1; off < 64; off <<= 1) {
        s  += __shfl_xor(s, off, 64);
        ss += __shfl_xor(ss, off, 64);
    }
    __shared__ float rs[16], rss[16];
    int wid = tid >> 6;
    if ((tid & 63) == 0) { rs[wid] = s; rss[wid] = ss; }
    __syncthreads();
    if (tid == 0) {
        float ts = 0.f, tss = 0.f;
        #pragma unroll
        for (int i = 0; i < 16; ++i) { ts += rs[i]; tss += rss[i]; }
        const float n = 3 * W_ * C_;
        float mean = ts / n;
        float var  = tss / n - mean * mean;
        stats[blk] = make_float2(mean, rsqrtf(var + EPS_));
    }
}

// ---------------------------------------------------------------------------
// Kernel 2: fused GroupNorm-apply + QKV projection via MFMA.
// Grid = 3 * 576 ONE-WAVE blocks (6.75 blocks/CU -> fast ramp; measured
// ~4 us better than 4-wave blocks in R14).
// ---------------------------------------------------------------------------
__global__ __launch_bounds__(64)
void qkv_kernel(const float* __restrict__ x, const float2* __restrict__ stats,
                const float* __restrict__ gamma, const float* __restrict__ beta,
                const bf16* __restrict__ wqt, const bf16* __restrict__ wkt,
                const bf16* __restrict__ wvt,
                const float* __restrict__ bq, const float* __restrict__ bk,
                const float* __restrict__ bv,
                bf16* __restrict__ qb, bf16* __restrict__ kb, bf16* __restrict__ vt) {
    int blk = blockIdx.x;
    int w = blk / 576, tile = blk % 576;
    int n0 = tile * 32;
    int lane = threadIdx.x;
    int col = lane & 31, hh = lane >> 5;
    int token = n0 + col;

    short8 hf[6];
    load_hn_frags(x, stats, gamma, beta, token, hh, hf);

    if (w == 2) {
        int bb = n0 / HW_, nl0 = n0 % HW_;
        #pragma unroll
        for (int t = 0; t < 3; ++t) {
            int c = t * 32 + col;
            const bf16* wrow = wvt + (size_t)c * C_ + hh * 8;
            f32x16 acc = (f32x16)(0.f);
            #pragma unroll
            for (int s = 0; s < 6; ++s)
                acc = __builtin_amdgcn_mfma_f32_32x32x16_bf16(
                        hf[s], *(const short8*)(wrow + s * 16), acc, 0, 0, 0);
            float bias = bv[c];
            bf16* dst = vt + ((size_t)bb * C_ + c) * HW_ + nl0 + 4 * hh;
            #pragma unroll
            for (int g = 0; g < 4; ++g) {
                uint2 pk = make_uint2(pk_bf16(acc[4 * g] + bias, acc[4 * g + 1] + bias),
                                      pk_bf16(acc[4 * g + 2] + bias, acc[4 * g + 3] + bias));
                *(uint2*)(dst + 8 * g) = pk;
            }
        }
    } else {
        const bf16*  wt   = (w == 0) ? wqt : wkt;
        const float* bias = (w == 0) ? bq : bk;
        bf16*        dst  = (w == 0) ? qb : kb;
        float        scl  = (w == 0) ? SCL : 1.f;
        #pragma unroll
        for (int t = 0; t < 3; ++t) {
            const bf16* wrow = wt + (size_t)(t * 32 + col) * C_ + hh * 8;
            f32x16 acc = (f32x16)(0.f);
            #pragma unroll
            for (int s = 0; s < 6; ++s)
                acc = __builtin_amdgcn_mfma_f32_32x32x16_bf16(
                        *(const short8*)(wrow + s * 16), hf[s], acc, 0, 0, 0);
            #pragma unroll
            for (int g = 0; g < 4; ++g) {
                int nb = t * 32 + 8 * g + 4 * hh;
                float4 b4 = *(const float4*)(bias + nb);
                float v0 = (acc[4 * g]     + b4.x) * scl;
                float v1 = (acc[4 * g + 1] + b4.y) * scl;
                float v2 = (acc[4 * g + 2] + b4.z) * scl;
                float v3 = (acc[4 * g + 3] + b4.w) * scl;
                uint2 pk = make_uint2(pk_bf16(v0, v1), pk_bf16(v2, v3));
                *(uint2*)(dst + (size_t)token * C_ + nb) = pk;
            }
        }
    }
}

// ---------------------------------------------------------------------------
// Kernel 3: MFMA flash attention, software-pipelined (R15).
// Triple-buffered K/V in LDS; S^T for tile i+1 is computed (QK MFMA chain)
// in the SAME basic block as the softmax+pack of tile i, so the scheduler
// can interleave trans/VALU softmax into MFMA-chain stall slots and the
// MFMA->exp dependency spans a barrier instead of the critical path.
// 6-body unroll = LCM(3-buffer rotation, stA/stB ping-pong); last 6 bodies
// peeled so prefetch/QK guards constant-fold (no branches in hot bodies).
// launch_bounds(256,3): carried S + kf frags exceed the 128-reg cap of
// (256,4) (R14 spill lesson); cap ~170 avoids in-loop spills. LDS 39.9 KB
// -> 4 blocks/CU, >= grid's 4.5/CU average, so residency is unchanged.
// ---------------------------------------------------------------------------
__global__ __launch_bounds__(256, 3)
void attn_kernel(const bf16* __restrict__ qb, const bf16* __restrict__ kb,
                 const bf16* __restrict__ vt,
                 bf16* __restrict__ pob, float* __restrict__ pl) {
    __shared__ short Kbuf[3][32 * 100];   // 19.2 KB
    __shared__ short Vbuf[3][96 * 36];    // 20.7 KB

    int blk = blockIdx.x;
    int ks = blk & 7, qg = blk >> 3;      // qg 0..143
    int b = qg / 72, g72 = qg % 72;
    int n0 = g72 * 128;                    // 128 q-rows per block
    int tid = threadIdx.x;
    int wave = tid >> 6, lane = tid & 63;
    int col = lane & 31, hh = lane >> 5;

    const bf16* kbb = kb + ((size_t)b * HW_ + (size_t)ks * KRANGE) * C_;
    const bf16* vbb = vt + (size_t)b * C_ * HW_ + (size_t)ks * KRANGE;

    // --- persistent Q fragments: one 32-row tile per wave ---
    int n = n0 + wave * 32 + col;
    short8 qf[6];
    {
        const bf16* qrow = qb + (size_t)(b * HW_ + n) * C_ + hh * 8;
        #pragma unroll
        for (int s = 0; s < 6; ++s) qf[s] = *(const short8*)(qrow + s * 16);
    }

    f32x16 oa[3];
    #pragma unroll
    for (int t = 0; t < 3; ++t) oa[t] = (f32x16)(0.f);
    float l_run = 0.f;

    // --- staging geometry: threads 0..127 stage K (384 16B-chunks),
    //     threads 128..255 stage V (384 chunks, permuted columns) ---
    bool isK = (tid < 128);
    int t128 = tid & 127;
    int ldsA[3], ldsB[3], goff[3];
    #pragma unroll
    for (int j = 0; j < 3; ++j) {
        int c = t128 + 128 * j;
        if (isK) {
            ldsA[j] = (c / 12) * 100 + (c % 12) * 8;
            ldsB[j] = ldsA[j] + 4;
            goff[j] = c * 8;
        } else {
            int rw = c >> 2, g = c & 3;
            // V permutation: key-group 2g -> pos-group 2g-(g&1); 2g+1 -> 2g+2-(g&1)
            ldsA[j] = rw * 36 + (2 * g - (g & 1)) * 4;
            ldsB[j] = rw * 36 + (2 * g + 2 - (g & 1)) * 4;
            goff[j] = rw * HW_ + g * 8;
        }
    }
    const bf16* gbase = isK ? kbb : vbb;
    const int itstep = isK ? (32 * C_) : 32;

    // --- prologue: stage tiles 0 and 1 into buffers 0 and 1 ---
    {
        short* sb0 = isK ? Kbuf[0] : Vbuf[0];
        short* sb1 = isK ? Kbuf[1] : Vbuf[1];
        #pragma unroll
        for (int j = 0; j < 3; ++j) {
            int4 r = *(const int4*)(gbase + goff[j]);
            *(int2*)(sb0 + ldsA[j]) = make_int2(r.x, r.y);
            *(int2*)(sb0 + ldsB[j]) = make_int2(r.z, r.w);
        }
        #pragma unroll
        for (int j = 0; j < 3; ++j) {
            int4 r = *(const int4*)(gbase + itstep + goff[j]);
            *(int2*)(sb1 + ldsA[j]) = make_int2(r.x, r.y);
            *(int2*)(sb1 + ldsB[j]) = make_int2(r.z, r.w);
        }
    }
    __syncthreads();

    union FU { uint32_t w[4]; short8 v; };

    // --- pre-loop: S^T(0) = K(0) . Q^T from buffer 0 ---
    f32x16 stA, stB;
    {
        const short* Kc = Kbuf[0];
        short8 kf[6];
        #pragma unroll
        for (int s = 0; s < 6; ++s)
            kf[s] = lds_frag(Kc + col * 100 + s * 16 + hh * 8);
        stA = (f32x16)(0.f);
        #pragma unroll
        for (int s = 0; s < 6; ++s)
            stA = __builtin_amdgcn_mfma_f32_32x32x16_bf16(kf[s], qf[s], stA, 0, 0, 0);
    }

// Body invariant at entry: SC = S^T(IT); tile IT in buf[CUR], tile IT+1 in
// buf[NXT] (both readable since the barrier ending body IT-1 / the prologue).
// Steps: issue global prefetch of tile IT+2 -> QK(IT+1) into SN (reads
// buf[NXT]) -> softmax+pack of SC -> PV from buf[CUR] -> LDS-write tile IT+2
// into buf[WRT] (= buf holding tile IT-1, already consumed) -> barrier.
#define ATT_BODY(IT, CUR, NXT, WRT, SC, SN, PRE1, PRE2)                          \
    {                                                                            \
        int4 r0, r1, r2;                                                         \
        if (PRE2) {                                                              \
            const bf16* g = gbase + (size_t)((IT) + 2) * itstep;                 \
            r0 = *(const int4*)(g + goff[0]);                                    \
            r1 = *(const int4*)(g + goff[1]);                                    \
            r2 = *(const int4*)(g + goff[2]);                                    \
        }                                                                        \
        if (PRE1) {                                                              \
            const short* Kc = Kbuf[NXT];                                         \
            short8 kf0 = lds_frag(Kc + col * 100 + 0 * 16 + hh * 8);             \
            short8 kf1 = lds_frag(Kc + col * 100 + 1 * 16 + hh * 8);             \
            short8 kf2 = lds_frag(Kc + col * 100 + 2 * 16 + hh * 8);             \
            short8 kf3 = lds_frag(Kc + col * 100 + 3 * 16 + hh * 8);             \
            short8 kf4 = lds_frag(Kc + col * 100 + 4 * 16 + hh * 8);             \
            short8 kf5 = lds_frag(Kc + col * 100 + 5 * 16 + hh * 8);             \
            SN = (f32x16)(0.f);                                                  \
            SN = __builtin_amdgcn_mfma_f32_32x32x16_bf16(kf0, qf[0], SN, 0, 0, 0); \
            SN = __builtin_amdgcn_mfma_f32_32x32x16_bf16(kf1, qf[1], SN, 0, 0, 0); \
            SN = __builtin_amdgcn_mfma_f32_32x32x16_bf16(kf2, qf[2], SN, 0, 0, 0); \
            SN = __builtin_amdgcn_mfma_f32_32x32x16_bf16(kf3, qf[3], SN, 0, 0, 0); \
            SN = __builtin_amdgcn_mfma_f32_32x32x16_bf16(kf4, qf[4], SN, 0, 0, 0); \
            SN = __builtin_amdgcn_mfma_f32_32x32x16_bf16(kf5, qf[5], SN, 0, 0, 0); \
        }                                                                        \
        float p[16], ls = 0.f;                                                   \
        _Pragma("unroll")                                                        \
        for (int i = 0; i < 16; ++i) { p[i] = fexp2(SC[i]); ls += p[i]; }        \
        l_run += ls;                                                             \
        FU f0, f1;                                                               \
        _Pragma("unroll")                                                        \
        for (int j = 0; j < 4; ++j) {                                            \
            f0.w[j] = pk_bf16(p[2 * j],     p[2 * j + 1]);                       \
            f1.w[j] = pk_bf16(p[8 + 2 * j], p[8 + 2 * j + 1]);                   \
        }                                                                        \
        {                                                                        \
            const short* Vc = Vbuf[CUR];                                         \
            _Pragma("unroll")                                                    \
            for (int t = 0; t < 3; ++t) {                                        \
                const short* vr = Vc + (32 * t + col) * 36 + hh * 8;             \
                short8 vf0 = lds_frag(vr);                                       \
                short8 vf1 = lds_frag(vr + 16);                                  \
                oa[t] = __builtin_amdgcn_mfma_f32_32x32x16_bf16(vf0, f0.v, oa[t], 0, 0, 0); \
                oa[t] = __builtin_amdgcn_mfma_f32_32x32x16_bf16(vf1, f1.v, oa[t], 0, 0, 0); \
            }                                                                    \
        }                                                                        \
        if (PRE2) {                                                              \
            short* sb = isK ? Kbuf[WRT] : Vbuf[WRT];                             \
            *(int2*)(sb + ldsA[0]) = make_int2(r0.x, r0.y);                      \
            *(int2*)(sb + ldsB[0]) = make_int2(r0.z, r0.w);                      \
            *(int2*)(sb + ldsA[1]) = make_int2(r1.x, r1.y);                      \
            *(int2*)(sb + ldsB[1]) = make_int2(r1.z, r1.w);                      \
            *(int2*)(sb + ldsA[2]) = make_int2(r2.x, r2.y);                      \
            *(int2*)(sb + ldsB[2]) = make_int2(r2.z, r2.w);                      \
        }                                                                        \
        __syncthreads();                                                         \
    }

    // main loop: it = 0..29 (all guards compile-time true)
    #pragma unroll 1
    for (int itb = 0; itb < ATT_NIT - 6; itb += 6) {
        ATT_BODY(itb + 0, 0, 1, 2, stA, stB, 1, 1)
        ATT_BODY(itb + 1, 1, 2, 0, stB, stA, 1, 1)
        ATT_BODY(itb + 2, 2, 0, 1, stA, stB, 1, 1)
        ATT_BODY(itb + 3, 0, 1, 2, stB, stA, 1, 1)
        ATT_BODY(itb + 4, 1, 2, 0, stA, stB, 1, 1)
        ATT_BODY(itb + 5, 2, 0, 1, stB, stA, 1, 1)
    }
    // peeled tail: it = 30..35, guards fold to constants
    ATT_BODY(30, 0, 1, 2, stA, stB, 1, 1)
    ATT_BODY(31, 1, 2, 0, stB, stA, 1, 1)
    ATT_BODY(32, 2, 0, 1, stA, stB, 1, 1)
    ATT_BODY(33, 0, 1, 2, stB, stA, 1, 1)
    ATT_BODY(34, 1, 2, 0, stA, stB, 1, 0)
    ATT_BODY(35, 2, 0, 1, stB, stA, 0, 0)
#undef ATT_BODY

    // --- epilogue: store unnormalized partial O (bf16) and partial l ---
    {
        size_t bq = (size_t)b * HW_ + n;
        float lt = l_run + __shfl_xor(l_run, 32, 64);
        if (hh == 0) pl[(size_t)ks * NT_ + bq] = lt;
        #pragma unroll
        for (int t = 0; t < 3; ++t)
            #pragma unroll
            for (int g = 0; g < 4; ++g) {
                int c0 = t * 32 + 8 * g + 4 * hh;
                uint2 pk = make_uint2(
                    pk_bf16(oa[t][4 * g],     oa[t][4 * g + 1]),
                    pk_bf16(oa[t][4 * g + 2], oa[t][4 * g + 3]));
                *(uint2*)(pob + ((size_t)ks * NT_ + bq) * C_ + c0) = pk;
            }
    }
}

// ---------------------------------------------------------------------------
// Kernel 4: fused merge + output projection + residual.
// Grid = 576 blocks x 256 thr. Coalesced merge of 8 key-split partials into
// an LDS tile (stride 100 -> 2-way banks, free), then waves 0-2 MFMA GEMM.
// ---------------------------------------------------------------------------
__global__ __launch_bounds__(256)
void out_kernel(const float* __restrict__ x,
                const bf16* __restrict__ pob, const float* __restrict__ pl,
                const bf16* __restrict__ wpt, const float* __restrict__ bp,
                float* __restrict__ out) {
    __shared__ short ofs[32 * 100];   // 6.4 KB merged O tile (padded stride)
    __shared__ float linv_s[32];

    int tile = blockIdx.x;            // 0..575
    int n0 = tile * 32;
    int tid = threadIdx.x;

    if (tid < 32) {
        int token = n0 + tid;
        float l = 0.f;
        #pragma unroll
        for (int ksp = 0; ksp < KSPLIT; ++ksp) l += pl[(size_t)ksp * NT_ + token];
        linv_s[tid] = 1.f / l;
    }
    __syncthreads();

    for (int pos = tid; pos < 384; pos += 256) {
        int token = pos / 12, c8 = (pos % 12) * 8;
        float acc[8] = {0.f, 0.f, 0.f, 0.f, 0.f, 0.f, 0.f, 0.f};
        #pragma unroll
        for (int ksp = 0; ksp < KSPLIT; ++ksp) {
            uint4 u = *(const uint4*)(pob + ((size_t)ksp * NT_ + n0 + token) * C_ + c8);
            acc[0] += bl(u.x); acc[1] += bh(u.x);
            acc[2] += bl(u.y); acc[3] += bh(u.y);
            acc[4] += bl(u.z); acc[5] += bh(u.z);
            acc[6] += bl(u.w); acc[7] += bh(u.w);
        }
        float inv = linv_s[token];
        short* dst = ofs + token * 100 + c8;
        *(int2*)(dst)     = make_int2(pk_bf16(acc[0] * inv, acc[1] * inv),
                                      pk_bf16(acc[2] * inv, acc[3] * inv));
        *(int2*)(dst + 4) = make_int2(pk_bf16(acc[4] * inv, acc[5] * inv),
                                      pk_bf16(acc[6] * inv, acc[7] * inv));
    }
    __syncthreads();

    int wave = tid >> 6;
    if (wave >= 3) return;
    int lane = tid & 63, col = lane & 31, hh = lane >> 5;
    int t = wave;
    int token = n0 + col;

    short8 of[6];
    #pragma unroll
    for (int s = 0; s < 6; ++s)
        of[s] = lds_frag(ofs + col * 100 + s * 16 + hh * 8);

    f32x16 acc = (f32x16)(0.f);
    const bf16* wrow = wpt + (size_t)(t * 32 + col) * C_ + hh * 8;
    #pragma unroll
    for (int s = 0; s < 6; ++s)
        acc = __builtin_amdgcn_mfma_f32_32x32x16_bf16(
                *(const short8*)(wrow + s * 16), of[s], acc, 0, 0, 0);
    #pragma unroll
    for (int g = 0; g < 4; ++g) {
        int nb = t * 32 + 8 * g + 4 * hh;
        float4 b4 = *(const float4*)(bp + nb);
        float4 xv = *(const float4*)(x + (size_t)token * C_ + nb);
        float4 rr;
        rr.x = xv.x + acc[4 * g]     + b4.x;
        rr.y = xv.y + acc[4 * g + 1] + b4.y;
        rr.z = xv.z + acc[4 * g + 2] + b4.z;
        rr.w = xv.w + acc[4 * g + 3] + b4.w;
        *(float4*)(out + (size_t)token * C_ + nb) = rr;
    }
}

// ---------------------------------------------------------------------------
extern "C" void kernel_launch(void* const* d_in, const int* in_sizes, int n_in,
                              void* d_out, int out_size, void* d_ws, size_t ws_size,
                              hipStream_t stream) {
    const float* x     = (const float*)d_in[0];
    const float* gamma = (const float*)d_in[1];
    const float* beta  = (const float*)d_in[2];
    const float* Wq    = (const float*)d_in[3];
    const float* bq    = (const float*)d_in[4];
    const float* Wk    = (const float*)d_in[5];
    const float* bk    = (const float*)d_in[6];
    const float* Wv    = (const float*)d_in[7];
    const float* bv    = (const float*)d_in[8];
    const float* Wp    = (const float*)d_in[9];
    const float* bp    = (const float*)d_in[10];
    float* out = (float*)d_out;

    char* ws = (char*)d_ws;
    const size_t TB = (size_t)NT_ * C_ * 2;   // 3.54 MB per bf16 tensor
    bf16* qb  = (bf16*)(ws);
    bf16* kb  = (bf16*)(ws + TB);
    bf16* vt  = (bf16*)(ws + 2 * TB);
    bf16* wqt = (bf16*)(ws + 3 * TB);
    bf16* wkt = (bf16*)(ws + 3 * TB + 18432);
    bf16* wvt = (bf16*)(ws + 3 * TB + 2 * 18432);
    bf16* wpt = (bf16*)(ws + 3 * TB + 3 * 18432);
    float2* stats = (float2*)(ws + 3 * TB + 4 * 18432);
    bf16*  pob = (bf16*)(ws + 3 * TB + 4 * 18432 + 512);          // 28.3 MB
    float* pl  = (float*)(ws + 3 * TB + 4 * 18432 + 512
                          + (size_t)KSPLIT * NT_ * C_ * 2);        // 0.6 MB

    hipLaunchKernelGGL(stats_prep_kernel, dim3(68), dim3(1024), 0, stream,
                       x, stats, Wq, Wk, Wv, Wp, wqt, wkt, wvt, wpt);
    hipLaunchKernelGGL(qkv_kernel, dim3(3 * 576), dim3(64), 0, stream,
                       x, stats, gamma, beta, wqt, wkt, wvt, bq, bk, bv, qb, kb, vt);
    hipLaunchKernelGGL(attn_kernel, dim3(1152), dim3(256), 0, stream,
                       qb, kb, vt, pob, pl);
    hipLaunchKernelGGL(out_kernel, dim3(576), dim3(256), 0, stream,
                       x, pob, pl, wpt, bp, out);
}

// Round 3
// 199.868 us; speedup vs baseline: 1.5213x; 1.5213x over previous
//
#include <hip/hip_runtime.h>
#include <hip/hip_bf16.h>
#include <stdint.h>

// Problem constants
#define B_   2
#define H_   96
#define W_   96
#define C_   96
#define HW_  (H_ * W_)       // 9216
#define NT_  (B_ * HW_)      // 18432
#define EPS_ 1e-5f
#define KSPLIT  8
#define KRANGE  (HW_ / KSPLIT)   // 1152 keys per block
#define ATT_NIT (KRANGE / 32)    // 36 iterations
// softmax scale with log2(e) folded in so native exp2 (v_exp_f32) works
#define SCL (0.10206207261596575f * 1.4426950408889634f)

typedef __hip_bfloat16 bf16;
typedef __attribute__((ext_vector_type(8))) short short8;   // 8 bf16 (MFMA A/B frag)
typedef __attribute__((ext_vector_type(16))) float f32x16;  // MFMA C/D frag

union FU { uint32_t w[4]; short8 v; };

// Fast bf16x2 pack: round-half-up (+0x8000) then v_perm picks the two high
// halves. low16 = bf16(a), high16 = bf16(b).
__device__ __forceinline__ uint32_t pk_bf16(float a, float b) {
    uint32_t ua = __float_as_uint(a) + 0x8000u;
    uint32_t ub = __float_as_uint(b) + 0x8000u;
    return __builtin_amdgcn_perm(ub, ua, 0x07060302u);
}
__device__ __forceinline__ float bl(uint32_t u) { uint32_t x = u << 16;         return *(float*)&x; }
__device__ __forceinline__ float bh(uint32_t u) { uint32_t x = u & 0xffff0000u; return *(float*)&x; }
// raw v_exp_f32 (2-ulp; inputs bounded, result feeds bf16 -> plenty accurate)
__device__ __forceinline__ float fexp2(float x) { return __builtin_amdgcn_exp2f(x); }
// 16B LDS fragment read as 2x ds_read_b64 (8B-aligned; padded strides keep
// bank aliasing at 2-way which is free on gfx950)
__device__ __forceinline__ short8 lds_frag(const short* p) {
    union { int2 h[2]; short8 v; } t;
    t.h[0] = *(const int2*)(p);
    t.h[1] = *(const int2*)(p + 4);
    return t.v;
}

// Rebuild one lane's 48-channel GroupNorm'd fragment set from x + stats.
__device__ __forceinline__ void load_hn_frags(
        const float* __restrict__ x, const float2* __restrict__ stats,
        const float* __restrict__ gamma, const float* __restrict__ beta,
        int token, int hh, short8* hf) {
    int b = token / HW_;
    int h = (token % HW_) / W_;
    float2 st = stats[b * 32 + h / 3];
    float g0 = gamma[h];
    float ga = g0 * st.y;
    float be = beta[h] - st.x * st.y * g0;
    const float* xr = x + (size_t)token * C_ + hh * 8;
    #pragma unroll
    for (int s = 0; s < 6; ++s) {
        float4 a = *(const float4*)(xr + s * 16);
        float4 c = *(const float4*)(xr + s * 16 + 4);
        union { uint32_t w[4]; short8 v; } f;
        f.w[0] = pk_bf16(a.x * ga + be, a.y * ga + be);
        f.w[1] = pk_bf16(a.z * ga + be, a.w * ga + be);
        f.w[2] = pk_bf16(c.x * ga + be, c.y * ga + be);
        f.w[3] = pk_bf16(c.z * ga + be, c.w * ga + be);
        hf[s] = f.v;
    }
}

// ---------------------------------------------------------------------------
// Kernel 1: GroupNorm stats (blocks 0..63, float4 scan + shuffle reduce)
//           + weight transpose (blocks 64..67)
// ---------------------------------------------------------------------------
__global__ __launch_bounds__(1024)
void stats_prep_kernel(const float* __restrict__ x, float2* __restrict__ stats,
                       const float* __restrict__ Wq, const float* __restrict__ Wk,
                       const float* __restrict__ Wv, const float* __restrict__ Wp,
                       bf16* __restrict__ wqt, bf16* __restrict__ wkt,
                       bf16* __restrict__ wvt, bf16* __restrict__ wpt) {
    int blk = blockIdx.x;
    int tid = threadIdx.x;
    if (blk >= 64) {
        int wsel = blk - 64;
        const float* S = (wsel == 0) ? Wq : (wsel == 1) ? Wk : (wsel == 2) ? Wv : Wp;
        bf16* D = (wsel == 0) ? wqt : (wsel == 1) ? wkt : (wsel == 2) ? wvt : wpt;
        for (int i = tid; i < C_ * C_; i += 1024) {
            int r = i / C_, c = i % C_;
            D[c * C_ + r] = __float2bfloat16(S[r * C_ + c]);
        }
        return;
    }
    int b = blk >> 5, g = blk & 31;
    const int n4 = 3 * W_ * C_ / 4;   // 6912 float4s
    const float4* xb = (const float4*)(x + (size_t)(b * H_ + 3 * g) * (W_ * C_));
    float s = 0.f, ss = 0.f;
    for (int i = tid; i < n4; i += 1024) {
        float4 v = xb[i];
        s  += v.x + v.y + v.z + v.w;
        ss += v.x * v.x + v.y * v.y + v.z * v.z + v.w * v.w;
    }
    // wave shuffle reduce
    #pragma unroll
    for (int off = 1; off < 64; off <<= 1) {
        s  += __shfl_xor(s, off, 64);
        ss += __shfl_xor(ss, off, 64);
    }
    __shared__ float rs[16], rss[16];
    int wid = tid >> 6;
    if ((tid & 63) == 0) { rs[wid] = s; rss[wid] = ss; }
    __syncthreads();
    if (tid == 0) {
        float ts = 0.f, tss = 0.f;
        #pragma unroll
        for (int i = 0; i < 16; ++i) { ts += rs[i]; tss += rss[i]; }
        const float n = 3 * W_ * C_;
        float mean = ts / n;
        float var  = tss / n - mean * mean;
        stats[blk] = make_float2(mean, rsqrtf(var + EPS_));
    }
}

// ---------------------------------------------------------------------------
// Kernel 2: fused GroupNorm-apply + QKV projection via MFMA.
// Grid = 3 * 576 ONE-WAVE blocks (6.75 blocks/CU -> fast ramp; measured
// ~4 us better than 4-wave blocks in R14).
// ---------------------------------------------------------------------------
__global__ __launch_bounds__(64)
void qkv_kernel(const float* __restrict__ x, const float2* __restrict__ stats,
                const float* __restrict__ gamma, const float* __restrict__ beta,
                const bf16* __restrict__ wqt, const bf16* __restrict__ wkt,
                const bf16* __restrict__ wvt,
                const float* __restrict__ bq, const float* __restrict__ bk,
                const float* __restrict__ bv,
                bf16* __restrict__ qb, bf16* __restrict__ kb, bf16* __restrict__ vt) {
    int blk = blockIdx.x;
    int w = blk / 576, tile = blk % 576;
    int n0 = tile * 32;
    int lane = threadIdx.x;
    int col = lane & 31, hh = lane >> 5;
    int token = n0 + col;

    short8 hf[6];
    load_hn_frags(x, stats, gamma, beta, token, hh, hf);

    if (w == 2) {
        int bb = n0 / HW_, nl0 = n0 % HW_;
        #pragma unroll
        for (int t = 0; t < 3; ++t) {
            int c = t * 32 + col;
            const bf16* wrow = wvt + (size_t)c * C_ + hh * 8;
            f32x16 acc = (f32x16)(0.f);
            #pragma unroll
            for (int s = 0; s < 6; ++s)
                acc = __builtin_amdgcn_mfma_f32_32x32x16_bf16(
                        hf[s], *(const short8*)(wrow + s * 16), acc, 0, 0, 0);
            float bias = bv[c];
            bf16* dst = vt + ((size_t)bb * C_ + c) * HW_ + nl0 + 4 * hh;
            #pragma unroll
            for (int g = 0; g < 4; ++g) {
                uint2 pk = make_uint2(pk_bf16(acc[4 * g] + bias, acc[4 * g + 1] + bias),
                                      pk_bf16(acc[4 * g + 2] + bias, acc[4 * g + 3] + bias));
                *(uint2*)(dst + 8 * g) = pk;
            }
        }
    } else {
        const bf16*  wt   = (w == 0) ? wqt : wkt;
        const float* bias = (w == 0) ? bq : bk;
        bf16*        dst  = (w == 0) ? qb : kb;
        float        scl  = (w == 0) ? SCL : 1.f;
        #pragma unroll
        for (int t = 0; t < 3; ++t) {
            const bf16* wrow = wt + (size_t)(t * 32 + col) * C_ + hh * 8;
            f32x16 acc = (f32x16)(0.f);
            #pragma unroll
            for (int s = 0; s < 6; ++s)
                acc = __builtin_amdgcn_mfma_f32_32x32x16_bf16(
                        *(const short8*)(wrow + s * 16), hf[s], acc, 0, 0, 0);
            #pragma unroll
            for (int g = 0; g < 4; ++g) {
                int nb = t * 32 + 8 * g + 4 * hh;
                float4 b4 = *(const float4*)(bias + nb);
                float v0 = (acc[4 * g]     + b4.x) * scl;
                float v1 = (acc[4 * g + 1] + b4.y) * scl;
                float v2 = (acc[4 * g + 2] + b4.z) * scl;
                float v3 = (acc[4 * g + 3] + b4.w) * scl;
                uint2 pk = make_uint2(pk_bf16(v0, v1), pk_bf16(v2, v3));
                *(uint2*)(dst + (size_t)token * C_ + nb) = pk;
            }
        }
    }
}

// ---------------------------------------------------------------------------
// Kernel 3: MFMA flash attention, carried-P software pipeline (R16).
// R10 serial structure, except the PV of tile i-1 (6 MFMAs, reads Vbuf two
// barriers old) executes in the same basic block as QK(i)+softmax(i): two
// independent MFMA chains fill each other's latency, and PV MFMAs fill the
// serial exp-chain slot. Only the packed P fragments (8 VGPRs) are carried
// across the barrier -- R15's carried-S (32 VGPRs) spilled (WRITE_SIZE
// 28->190 MB). V triple-buffered, K double-buffered: LDS 33.5 KB.
// Bodies are real template functions (compile-time buffer indices, real
// #pragma unroll in function scope -- avoids R15's macro/_Pragma hazard).
// launch_bounds(256,2): cap 256 regs so the cap itself can never force
// spills; expected landing ~150 unified -> 3 waves/SIMD.
// ---------------------------------------------------------------------------
template<int KB, int VPV, int VWR, bool DO_PV, bool PRE>
__device__ __forceinline__ void att_body(
        int it,
        short (&Kbuf)[2][3200], short (&Vbuf)[3][3456],
        const short8 (&qf)[6], f32x16 (&oa)[3],
        FU& f0, FU& f1, float& l_run,
        const bf16* gbase, int goff0, int goff1, int goff2,
        int ldsA0, int ldsA1, int ldsA2,
        int ldsB0, int ldsB1, int ldsB2,
        int itstep, bool isK, int col, int hh) {
    // global prefetch of tile it+1 (consumed at the LDS-write below)
    int4 r0, r1, r2;
    if (PRE) {
        const bf16* g = gbase + (size_t)(it + 1) * itstep;
        r0 = *(const int4*)(g + goff0);
        r1 = *(const int4*)(g + goff1);
        r2 = *(const int4*)(g + goff2);
    }
    // snapshot previous tile's packed P before this body overwrites f0/f1
    FU p0, p1;
    p0.v = f0.v; p1.v = f1.v;

    __builtin_amdgcn_s_setprio(1);
    // --- QK chain: S^T(it) = K(it) . Q^T ---
    const short* Kc = Kbuf[KB];
    short8 kf0 = lds_frag(Kc + col * 100 + 0 * 16 + hh * 8);
    short8 kf1 = lds_frag(Kc + col * 100 + 1 * 16 + hh * 8);
    short8 kf2 = lds_frag(Kc + col * 100 + 2 * 16 + hh * 8);
    short8 kf3 = lds_frag(Kc + col * 100 + 3 * 16 + hh * 8);
    short8 kf4 = lds_frag(Kc + col * 100 + 4 * 16 + hh * 8);
    short8 kf5 = lds_frag(Kc + col * 100 + 5 * 16 + hh * 8);
    f32x16 st = (f32x16)(0.f);
    st = __builtin_amdgcn_mfma_f32_32x32x16_bf16(kf0, qf[0], st, 0, 0, 0);
    st = __builtin_amdgcn_mfma_f32_32x32x16_bf16(kf1, qf[1], st, 0, 0, 0);
    st = __builtin_amdgcn_mfma_f32_32x32x16_bf16(kf2, qf[2], st, 0, 0, 0);
    st = __builtin_amdgcn_mfma_f32_32x32x16_bf16(kf3, qf[3], st, 0, 0, 0);
    st = __builtin_amdgcn_mfma_f32_32x32x16_bf16(kf4, qf[4], st, 0, 0, 0);
    st = __builtin_amdgcn_mfma_f32_32x32x16_bf16(kf5, qf[5], st, 0, 0, 0);

    // --- PV of tile it-1: independent of the QK chain above ---
    if (DO_PV) {
        const short* Vc = Vbuf[VPV];
        #pragma unroll
        for (int t = 0; t < 3; ++t) {
            const short* vr = Vc + (32 * t + col) * 36 + hh * 8;
            short8 vf0 = lds_frag(vr);
            short8 vf1 = lds_frag(vr + 16);
            oa[t] = __builtin_amdgcn_mfma_f32_32x32x16_bf16(vf0, p0.v, oa[t], 0, 0, 0);
            oa[t] = __builtin_amdgcn_mfma_f32_32x32x16_bf16(vf1, p1.v, oa[t], 0, 0, 0);
        }
    }

    // --- softmax + pack of tile it (consumed by next body's PV) ---
    float p[16], ls = 0.f;
    #pragma unroll
    for (int i = 0; i < 16; ++i) { p[i] = fexp2(st[i]); ls += p[i]; }
    l_run += ls;
    #pragma unroll
    for (int j = 0; j < 4; ++j) {
        f0.w[j] = pk_bf16(p[2 * j],     p[2 * j + 1]);
        f1.w[j] = pk_bf16(p[8 + 2 * j], p[8 + 2 * j + 1]);
    }
    __builtin_amdgcn_s_setprio(0);

    // --- LDS-write tile it+1 into the free buffer ---
    if (PRE) {
        short* sb = isK ? (short*)Kbuf[KB ^ 1] : (short*)Vbuf[VWR];
        *(int2*)(sb + ldsA0) = make_int2(r0.x, r0.y);
        *(int2*)(sb + ldsB0) = make_int2(r0.z, r0.w);
        *(int2*)(sb + ldsA1) = make_int2(r1.x, r1.y);
        *(int2*)(sb + ldsB1) = make_int2(r1.z, r1.w);
        *(int2*)(sb + ldsA2) = make_int2(r2.x, r2.y);
        *(int2*)(sb + ldsB2) = make_int2(r2.z, r2.w);
    }
    __syncthreads();
}

__global__ __launch_bounds__(256, 2)
void attn_kernel(const bf16* __restrict__ qb, const bf16* __restrict__ kb,
                 const bf16* __restrict__ vt,
                 bf16* __restrict__ pob, float* __restrict__ pl) {
    __shared__ short Kbuf[2][32 * 100];   // 12.8 KB
    __shared__ short Vbuf[3][96 * 36];    // 20.7 KB

    int blk = blockIdx.x;
    int ks = blk & 7, qg = blk >> 3;      // qg 0..143
    int b = qg / 72, g72 = qg % 72;
    int n0 = g72 * 128;                    // 128 q-rows per block
    int tid = threadIdx.x;
    int wave = tid >> 6, lane = tid & 63;
    int col = lane & 31, hh = lane >> 5;

    const bf16* kbb = kb + ((size_t)b * HW_ + (size_t)ks * KRANGE) * C_;
    const bf16* vbb = vt + (size_t)b * C_ * HW_ + (size_t)ks * KRANGE;

    // --- persistent Q fragments: one 32-row tile per wave ---
    int n = n0 + wave * 32 + col;
    short8 qf[6];
    {
        const bf16* qrow = qb + (size_t)(b * HW_ + n) * C_ + hh * 8;
        #pragma unroll
        for (int s = 0; s < 6; ++s) qf[s] = *(const short8*)(qrow + s * 16);
    }

    f32x16 oa[3];
    #pragma unroll
    for (int t = 0; t < 3; ++t) oa[t] = (f32x16)(0.f);
    float l_run = 0.f;

    // --- staging geometry: threads 0..127 stage K (384 16B-chunks),
    //     threads 128..255 stage V (384 chunks, permuted columns) ---
    bool isK = (tid < 128);
    int t128 = tid & 127;
    int ldsA[3], ldsB[3], goff[3];
    #pragma unroll
    for (int j = 0; j < 3; ++j) {
        int c = t128 + 128 * j;
        if (isK) {
            ldsA[j] = (c / 12) * 100 + (c % 12) * 8;
            ldsB[j] = ldsA[j] + 4;
            goff[j] = c * 8;
        } else {
            int rw = c >> 2, g = c & 3;
            // V permutation: key-group 2g -> pos-group 2g-(g&1); 2g+1 -> 2g+2-(g&1)
            ldsA[j] = rw * 36 + (2 * g - (g & 1)) * 4;
            ldsB[j] = rw * 36 + (2 * g + 2 - (g & 1)) * 4;
            goff[j] = rw * HW_ + g * 8;
        }
    }
    const bf16* gbase = isK ? kbb : vbb;
    const int itstep = isK ? (32 * C_) : 32;

    // --- prologue: stage tile 0 into K0/V0 ---
    {
        short* sb = isK ? (short*)Kbuf[0] : (short*)Vbuf[0];
        #pragma unroll
        for (int j = 0; j < 3; ++j) {
            int4 r = *(const int4*)(gbase + goff[j]);
            *(int2*)(sb + ldsA[j]) = make_int2(r.x, r.y);
            *(int2*)(sb + ldsB[j]) = make_int2(r.z, r.w);
        }
    }
    __syncthreads();

    FU f0, f1;
    f0.v = (short8)(short)0; f1.v = (short8)(short)0;

    #define ABODY(KB_, VPV_, VWR_, DOPV_, PRE_, IT_)                         \
        att_body<KB_, VPV_, VWR_, DOPV_, PRE_>(IT_, Kbuf, Vbuf, qf, oa,      \
            f0, f1, l_run, gbase, goff[0], goff[1], goff[2],                 \
            ldsA[0], ldsA[1], ldsA[2], ldsB[0], ldsB[1], ldsB[2],            \
            itstep, isK, col, hh)

    // body 0: QK(0) only, stage tile 1
    ABODY(0, 0, 1, 0, 1, 0);
    // bodies 1..30: uniform (pattern repeats every 6: lcm(K mod 2, V mod 3))
    #pragma unroll 1
    for (int ib = 1; ib <= 25; ib += 6) {
        ABODY(1, 0, 2, 1, 1, ib + 0);
        ABODY(0, 1, 0, 1, 1, ib + 1);
        ABODY(1, 2, 1, 1, 1, ib + 2);
        ABODY(0, 0, 2, 1, 1, ib + 3);
        ABODY(1, 1, 0, 1, 1, ib + 4);
        ABODY(0, 2, 1, 1, 1, ib + 5);
    }
    // peeled bodies 31..35 (35: last tile, no prefetch/stage)
    ABODY(1, 0, 2, 1, 1, 31);
    ABODY(0, 1, 0, 1, 1, 32);
    ABODY(1, 2, 1, 1, 1, 33);
    ABODY(0, 0, 2, 1, 1, 34);
    ABODY(1, 1, 0, 1, 0, 35);
    #undef ABODY

    // tail: PV(35) from Vbuf[2] (staged in body 34)
    {
        const short* Vc = Vbuf[2];
        #pragma unroll
        for (int t = 0; t < 3; ++t) {
            const short* vr = Vc + (32 * t + col) * 36 + hh * 8;
            short8 vf0 = lds_frag(vr);
            short8 vf1 = lds_frag(vr + 16);
            oa[t] = __builtin_amdgcn_mfma_f32_32x32x16_bf16(vf0, f0.v, oa[t], 0, 0, 0);
            oa[t] = __builtin_amdgcn_mfma_f32_32x32x16_bf16(vf1, f1.v, oa[t], 0, 0, 0);
        }
    }

    // --- epilogue: store unnormalized partial O (bf16) and partial l ---
    {
        size_t bq = (size_t)b * HW_ + n;
        float lt = l_run + __shfl_xor(l_run, 32, 64);
        if (hh == 0) pl[(size_t)ks * NT_ + bq] = lt;
        #pragma unroll
        for (int t = 0; t < 3; ++t)
            #pragma unroll
            for (int g = 0; g < 4; ++g) {
                int c0 = t * 32 + 8 * g + 4 * hh;
                uint2 pk = make_uint2(
                    pk_bf16(oa[t][4 * g],     oa[t][4 * g + 1]),
                    pk_bf16(oa[t][4 * g + 2], oa[t][4 * g + 3]));
                *(uint2*)(pob + ((size_t)ks * NT_ + bq) * C_ + c0) = pk;
            }
    }
}

// ---------------------------------------------------------------------------
// Kernel 4: fused merge + output projection + residual.
// Grid = 576 blocks x 256 thr. Coalesced merge of 8 key-split partials into
// an LDS tile (stride 100 -> 2-way banks, free), then waves 0-2 MFMA GEMM.
// ---------------------------------------------------------------------------
__global__ __launch_bounds__(256)
void out_kernel(const float* __restrict__ x,
                const bf16* __restrict__ pob, const float* __restrict__ pl,
                const bf16* __restrict__ wpt, const float* __restrict__ bp,
                float* __restrict__ out) {
    __shared__ short ofs[32 * 100];   // 6.4 KB merged O tile (padded stride)
    __shared__ float linv_s[32];

    int tile = blockIdx.x;            // 0..575
    int n0 = tile * 32;
    int tid = threadIdx.x;

    if (tid < 32) {
        int token = n0 + tid;
        float l = 0.f;
        #pragma unroll
        for (int ksp = 0; ksp < KSPLIT; ++ksp) l += pl[(size_t)ksp * NT_ + token];
        linv_s[tid] = 1.f / l;
    }
    __syncthreads();

    for (int pos = tid; pos < 384; pos += 256) {
        int token = pos / 12, c8 = (pos % 12) * 8;
        float acc[8] = {0.f, 0.f, 0.f, 0.f, 0.f, 0.f, 0.f, 0.f};
        #pragma unroll
        for (int ksp = 0; ksp < KSPLIT; ++ksp) {
            uint4 u = *(const uint4*)(pob + ((size_t)ksp * NT_ + n0 + token) * C_ + c8);
            acc[0] += bl(u.x); acc[1] += bh(u.x);
            acc[2] += bl(u.y); acc[3] += bh(u.y);
            acc[4] += bl(u.z); acc[5] += bh(u.z);
            acc[6] += bl(u.w); acc[7] += bh(u.w);
        }
        float inv = linv_s[token];
        short* dst = ofs + token * 100 + c8;
        *(int2*)(dst)     = make_int2(pk_bf16(acc[0] * inv, acc[1] * inv),
                                      pk_bf16(acc[2] * inv, acc[3] * inv));
        *(int2*)(dst + 4) = make_int2(pk_bf16(acc[4] * inv, acc[5] * inv),
                                      pk_bf16(acc[6] * inv, acc[7] * inv));
    }
    __syncthreads();

    int wave = tid >> 6;
    if (wave >= 3) return;
    int lane = tid & 63, col = lane & 31, hh = lane >> 5;
    int t = wave;
    int token = n0 + col;

    short8 of[6];
    #pragma unroll
    for (int s = 0; s < 6; ++s)
        of[s] = lds_frag(ofs + col * 100 + s * 16 + hh * 8);

    f32x16 acc = (f32x16)(0.f);
    const bf16* wrow = wpt + (size_t)(t * 32 + col) * C_ + hh * 8;
    #pragma unroll
    for (int s = 0; s < 6; ++s)
        acc = __builtin_amdgcn_mfma_f32_32x32x16_bf16(
                *(const short8*)(wrow + s * 16), of[s], acc, 0, 0, 0);
    #pragma unroll
    for (int g = 0; g < 4; ++g) {
        int nb = t * 32 + 8 * g + 4 * hh;
        float4 b4 = *(const float4*)(bp + nb);
        float4 xv = *(const float4*)(x + (size_t)token * C_ + nb);
        float4 rr;
        rr.x = xv.x + acc[4 * g]     + b4.x;
        rr.y = xv.y + acc[4 * g + 1] + b4.y;
        rr.z = xv.z + acc[4 * g + 2] + b4.z;
        rr.w = xv.w + acc[4 * g + 3] + b4.w;
        *(float4*)(out + (size_t)token * C_ + nb) = rr;
    }
}

// ---------------------------------------------------------------------------
extern "C" void kernel_launch(void* const* d_in, const int* in_sizes, int n_in,
                              void* d_out, int out_size, void* d_ws, size_t ws_size,
                              hipStream_t stream) {
    const float* x     = (const float*)d_in[0];
    const float* gamma = (const float*)d_in[1];
    const float* beta  = (const float*)d_in[2];
    const float* Wq    = (const float*)d_in[3];
    const float* bq    = (const float*)d_in[4];
    const float* Wk    = (const float*)d_in[5];
    const float* bk    = (const float*)d_in[6];
    const float* Wv    = (const float*)d_in[7];
    const float* bv    = (const float*)d_in[8];
    const float* Wp    = (const float*)d_in[9];
    const float* bp    = (const float*)d_in[10];
    float* out = (float*)d_out;

    char* ws = (char*)d_ws;
    const size_t TB = (size_t)NT_ * C_ * 2;   // 3.54 MB per bf16 tensor
    bf16* qb  = (bf16*)(ws);
    bf16* kb  = (bf16*)(ws + TB);
    bf16* vt  = (bf16*)(ws + 2 * TB);
    bf16* wqt = (bf16*)(ws + 3 * TB);
    bf16* wkt = (bf16*)(ws + 3 * TB + 18432);
    bf16* wvt = (bf16*)(ws + 3 * TB + 2 * 18432);
    bf16* wpt = (bf16*)(ws + 3 * TB + 3 * 18432);
    float2* stats = (float2*)(ws + 3 * TB + 4 * 18432);
    bf16*  pob = (bf16*)(ws + 3 * TB + 4 * 18432 + 512);          // 28.3 MB
    float* pl  = (float*)(ws + 3 * TB + 4 * 18432 + 512
                          + (size_t)KSPLIT * NT_ * C_ * 2);        // 0.6 MB

    hipLaunchKernelGGL(stats_prep_kernel, dim3(68), dim3(1024), 0, stream,
                       x, stats, Wq, Wk, Wv, Wp, wqt, wkt, wvt, wpt);
    hipLaunchKernelGGL(qkv_kernel, dim3(3 * 576), dim3(64), 0, stream,
                       x, stats, gamma, beta, wqt, wkt, wvt, bq, bk, bv, qb, kb, vt);
    hipLaunchKernelGGL(attn_kernel, dim3(1152), dim3(256), 0, stream,
                       qb, kb, vt, pob, pl);
    hipLaunchKernelGGL(out_kernel, dim3(576), dim3(256), 0, stream,
                       x, pob, pl, wpt, bp, out);
}

// Round 4
// 194.286 us; speedup vs baseline: 1.5650x; 1.0287x over previous
//
#include <hip/hip_runtime.h>
#include <hip/hip_bf16.h>
#include <stdint.h>

// Problem constants
#define B_   2
#define H_   96
#define W_   96
#define C_   96
#define HW_  (H_ * W_)       // 9216
#define NT_  (B_ * HW_)      // 18432
#define EPS_ 1e-5f
#define KSPLIT  8
#define KRANGE  (HW_ / KSPLIT)   // 1152 keys per block
#define ATT_NIT (KRANGE / 32)    // 36 iterations
// softmax scale with log2(e) folded in so native exp2 (v_exp_f32) works
#define SCL (0.10206207261596575f * 1.4426950408889634f)

typedef __hip_bfloat16 bf16;
typedef __attribute__((ext_vector_type(8))) short short8;   // 8 bf16 (MFMA A/B frag)
typedef __attribute__((ext_vector_type(16))) float f32x16;  // MFMA C/D frag

// Fast bf16x2 pack: round-half-up (+0x8000) then v_perm picks the two high
// halves. low16 = bf16(a), high16 = bf16(b).
__device__ __forceinline__ uint32_t pk_bf16(float a, float b) {
    uint32_t ua = __float_as_uint(a) + 0x8000u;
    uint32_t ub = __float_as_uint(b) + 0x8000u;
    return __builtin_amdgcn_perm(ub, ua, 0x07060302u);
}
__device__ __forceinline__ float bl(uint32_t u) { uint32_t x = u << 16;         return *(float*)&x; }
__device__ __forceinline__ float bh(uint32_t u) { uint32_t x = u & 0xffff0000u; return *(float*)&x; }
// raw v_exp_f32 (2-ulp; inputs bounded, result feeds bf16 -> plenty accurate)
__device__ __forceinline__ float fexp2(float x) { return __builtin_amdgcn_exp2f(x); }
// 16B LDS fragment read as 2x ds_read_b64 (8B-aligned; padded strides keep
// bank aliasing at 2-way which is free on gfx950)
__device__ __forceinline__ short8 lds_frag(const short* p) {
    union { int2 h[2]; short8 v; } t;
    t.h[0] = *(const int2*)(p);
    t.h[1] = *(const int2*)(p + 4);
    return t.v;
}

// Rebuild one lane's 48-channel GroupNorm'd fragment set from x + stats.
__device__ __forceinline__ void load_hn_frags(
        const float* __restrict__ x, const float2* __restrict__ stats,
        const float* __restrict__ gamma, const float* __restrict__ beta,
        int token, int hh, short8* hf) {
    int b = token / HW_;
    int h = (token % HW_) / W_;
    float2 st = stats[b * 32 + h / 3];
    float g0 = gamma[h];
    float ga = g0 * st.y;
    float be = beta[h] - st.x * st.y * g0;
    const float* xr = x + (size_t)token * C_ + hh * 8;
    #pragma unroll
    for (int s = 0; s < 6; ++s) {
        float4 a = *(const float4*)(xr + s * 16);
        float4 c = *(const float4*)(xr + s * 16 + 4);
        union { uint32_t w[4]; short8 v; } f;
        f.w[0] = pk_bf16(a.x * ga + be, a.y * ga + be);
        f.w[1] = pk_bf16(a.z * ga + be, a.w * ga + be);
        f.w[2] = pk_bf16(c.x * ga + be, c.y * ga + be);
        f.w[3] = pk_bf16(c.z * ga + be, c.w * ga + be);
        hf[s] = f.v;
    }
}

// ---------------------------------------------------------------------------
// Kernel 1: GroupNorm stats (blocks 0..63, float4 scan + shuffle reduce)
//           + weight transpose (blocks 64..67)
// ---------------------------------------------------------------------------
__global__ __launch_bounds__(1024)
void stats_prep_kernel(const float* __restrict__ x, float2* __restrict__ stats,
                       const float* __restrict__ Wq, const float* __restrict__ Wk,
                       const float* __restrict__ Wv, const float* __restrict__ Wp,
                       bf16* __restrict__ wqt, bf16* __restrict__ wkt,
                       bf16* __restrict__ wvt, bf16* __restrict__ wpt) {
    int blk = blockIdx.x;
    int tid = threadIdx.x;
    if (blk >= 64) {
        int wsel = blk - 64;
        const float* S = (wsel == 0) ? Wq : (wsel == 1) ? Wk : (wsel == 2) ? Wv : Wp;
        bf16* D = (wsel == 0) ? wqt : (wsel == 1) ? wkt : (wsel == 2) ? wvt : wpt;
        for (int i = tid; i < C_ * C_; i += 1024) {
            int r = i / C_, c = i % C_;
            D[c * C_ + r] = __float2bfloat16(S[r * C_ + c]);
        }
        return;
    }
    int b = blk >> 5, g = blk & 31;
    const int n4 = 3 * W_ * C_ / 4;   // 6912 float4s
    const float4* xb = (const float4*)(x + (size_t)(b * H_ + 3 * g) * (W_ * C_));
    float s = 0.f, ss = 0.f;
    for (int i = tid; i < n4; i += 1024) {
        float4 v = xb[i];
        s  += v.x + v.y + v.z + v.w;
        ss += v.x * v.x + v.y * v.y + v.z * v.z + v.w * v.w;
    }
    // wave shuffle reduce
    #pragma unroll
    for (int off = 1; off < 64; off <<= 1) {
        s  += __shfl_xor(s, off, 64);
        ss += __shfl_xor(ss, off, 64);
    }
    __shared__ float rs[16], rss[16];
    int wid = tid >> 6;
    if ((tid & 63) == 0) { rs[wid] = s; rss[wid] = ss; }
    __syncthreads();
    if (tid == 0) {
        float ts = 0.f, tss = 0.f;
        #pragma unroll
        for (int i = 0; i < 16; ++i) { ts += rs[i]; tss += rss[i]; }
        const float n = 3 * W_ * C_;
        float mean = ts / n;
        float var  = tss / n - mean * mean;
        stats[blk] = make_float2(mean, rsqrtf(var + EPS_));
    }
}

// ---------------------------------------------------------------------------
// Kernel 2: fused GroupNorm-apply + QKV projection via MFMA.
// Grid = 3 * 576 ONE-WAVE blocks (6.75 blocks/CU -> fast ramp; measured
// ~4 us better than 4-wave blocks in R14).
// ---------------------------------------------------------------------------
__global__ __launch_bounds__(64)
void qkv_kernel(const float* __restrict__ x, const float2* __restrict__ stats,
                const float* __restrict__ gamma, const float* __restrict__ beta,
                const bf16* __restrict__ wqt, const bf16* __restrict__ wkt,
                const bf16* __restrict__ wvt,
                const float* __restrict__ bq, const float* __restrict__ bk,
                const float* __restrict__ bv,
                bf16* __restrict__ qb, bf16* __restrict__ kb, bf16* __restrict__ vt) {
    int blk = blockIdx.x;
    int w = blk / 576, tile = blk % 576;
    int n0 = tile * 32;
    int lane = threadIdx.x;
    int col = lane & 31, hh = lane >> 5;
    int token = n0 + col;

    short8 hf[6];
    load_hn_frags(x, stats, gamma, beta, token, hh, hf);

    if (w == 2) {
        int bb = n0 / HW_, nl0 = n0 % HW_;
        #pragma unroll
        for (int t = 0; t < 3; ++t) {
            int c = t * 32 + col;
            const bf16* wrow = wvt + (size_t)c * C_ + hh * 8;
            f32x16 acc = (f32x16)(0.f);
            #pragma unroll
            for (int s = 0; s < 6; ++s)
                acc = __builtin_amdgcn_mfma_f32_32x32x16_bf16(
                        hf[s], *(const short8*)(wrow + s * 16), acc, 0, 0, 0);
            float bias = bv[c];
            bf16* dst = vt + ((size_t)bb * C_ + c) * HW_ + nl0 + 4 * hh;
            #pragma unroll
            for (int g = 0; g < 4; ++g) {
                uint2 pk = make_uint2(pk_bf16(acc[4 * g] + bias, acc[4 * g + 1] + bias),
                                      pk_bf16(acc[4 * g + 2] + bias, acc[4 * g + 3] + bias));
                *(uint2*)(dst + 8 * g) = pk;
            }
        }
    } else {
        const bf16*  wt   = (w == 0) ? wqt : wkt;
        const float* bias = (w == 0) ? bq : bk;
        bf16*        dst  = (w == 0) ? qb : kb;
        float        scl  = (w == 0) ? SCL : 1.f;
        #pragma unroll
        for (int t = 0; t < 3; ++t) {
            const bf16* wrow = wt + (size_t)(t * 32 + col) * C_ + hh * 8;
            f32x16 acc = (f32x16)(0.f);
            #pragma unroll
            for (int s = 0; s < 6; ++s)
                acc = __builtin_amdgcn_mfma_f32_32x32x16_bf16(
                        *(const short8*)(wrow + s * 16), hf[s], acc, 0, 0, 0);
            #pragma unroll
            for (int g = 0; g < 4; ++g) {
                int nb = t * 32 + 8 * g + 4 * hh;
                float4 b4 = *(const float4*)(bias + nb);
                float v0 = (acc[4 * g]     + b4.x) * scl;
                float v1 = (acc[4 * g + 1] + b4.y) * scl;
                float v2 = (acc[4 * g + 2] + b4.z) * scl;
                float v3 = (acc[4 * g + 3] + b4.w) * scl;
                uint2 pk = make_uint2(pk_bf16(v0, v1), pk_bf16(v2, v3));
                *(uint2*)(dst + (size_t)token * C_ + nb) = pk;
            }
        }
    }
}

// ---------------------------------------------------------------------------
// Kernel 3: MFMA flash attention, dual-Q per wave (R17).
// DIAGNOSIS: R10 is LDS-BW-bound (~670 of 128B/cyc LDS cycles per block-iter
// vs ~750 cyc measured period -> LDS port ~90% busy; all 4 waves read
// IDENTICAL kf/vf fragments = 4x redundancy). FIX: each wave holds TWO Q
// tiles (rows n, n+128) and two accumulator sets; the same kf feeds stA+stB
// and the same vf feeds both PV updates -> LDS bytes per unit work HALVED;
// binding resource flips to the MFMA pipe (floor 26 us).
// Code structure byte-identical to the proven R10 baseline (no carried state
// across barriers, no by-reference bodies -- both spilled in R15/R16); only
// variables are duplicated A/B. Block covers 256 q-rows x 32 keys; grid 576.
// launch_bounds(256,2): ~130 arch VGPR + 96 AGPR expected -> no spill, 8
// waves/CU (fine: BW-bound, not latency-bound).
// ---------------------------------------------------------------------------
__global__ __launch_bounds__(256, 2)
void attn_kernel(const bf16* __restrict__ qb, const bf16* __restrict__ kb,
                 const bf16* __restrict__ vt,
                 bf16* __restrict__ pob, float* __restrict__ pl) {
    __shared__ short Kbuf[2][32 * 100];   // 12.8 KB
    __shared__ short Vbuf[2][96 * 36];    // 13.8 KB

    int blk = blockIdx.x;
    int ks = blk & 7, qg = blk >> 3;      // qg 0..71
    int b = qg / 36, g36 = qg % 36;
    int n0 = g36 * 256;                    // 256 q-rows per block
    int tid = threadIdx.x;
    int wave = tid >> 6, lane = tid & 63;
    int col = lane & 31, hh = lane >> 5;

    const bf16* kbb = kb + ((size_t)b * HW_ + (size_t)ks * KRANGE) * C_;
    const bf16* vbb = vt + (size_t)b * C_ * HW_ + (size_t)ks * KRANGE;

    // --- persistent Q fragments: TWO 32-row tiles per wave (A: wave*32,
    //     B: wave*32+128) ---
    int nA = n0 + wave * 32 + col;
    int nB = nA + 128;
    short8 qfA[6], qfB[6];
    {
        const bf16* qrowA = qb + (size_t)(b * HW_ + nA) * C_ + hh * 8;
        const bf16* qrowB = qb + (size_t)(b * HW_ + nB) * C_ + hh * 8;
        #pragma unroll
        for (int s = 0; s < 6; ++s) qfA[s] = *(const short8*)(qrowA + s * 16);
        #pragma unroll
        for (int s = 0; s < 6; ++s) qfB[s] = *(const short8*)(qrowB + s * 16);
    }

    f32x16 oaA[3], oaB[3];
    #pragma unroll
    for (int t = 0; t < 3; ++t) { oaA[t] = (f32x16)(0.f); oaB[t] = (f32x16)(0.f); }
    float lA = 0.f, lB = 0.f;

    // --- staging geometry: threads 0..127 stage K (384 16B-chunks),
    //     threads 128..255 stage V (384 chunks, permuted columns) ---
    bool isK = (tid < 128);
    int t128 = tid & 127;
    int ldsA[3], ldsB[3], goff[3];
    #pragma unroll
    for (int j = 0; j < 3; ++j) {
        int c = t128 + 128 * j;
        if (isK) {
            ldsA[j] = (c / 12) * 100 + (c % 12) * 8;
            ldsB[j] = ldsA[j] + 4;
            goff[j] = c * 8;
        } else {
            int rw = c >> 2, g = c & 3;
            // V permutation: key-group 2g -> pos-group 2g-(g&1); 2g+1 -> 2g+2-(g&1)
            ldsA[j] = rw * 36 + (2 * g - (g & 1)) * 4;
            ldsB[j] = rw * 36 + (2 * g + 2 - (g & 1)) * 4;
            goff[j] = rw * HW_ + g * 8;
        }
    }
    const bf16* gbase = isK ? kbb : vbb;
    const int itstep = isK ? (32 * C_) : 32;

    // --- prologue: stage tile 0 into buffer 0 ---
    {
        short* sb = isK ? Kbuf[0] : Vbuf[0];
        #pragma unroll
        for (int j = 0; j < 3; ++j) {
            int4 r = *(const int4*)(gbase + goff[j]);
            *(int2*)(sb + ldsA[j]) = make_int2(r.x, r.y);
            *(int2*)(sb + ldsB[j]) = make_int2(r.z, r.w);
        }
    }
    __syncthreads();

    union FU { uint32_t w[4]; short8 v; };

    for (int it = 0; it < ATT_NIT; ++it) {
        int cur = it & 1;
        bool pre = (it + 1 < ATT_NIT);
        int4 r0, r1, r2;
        if (pre) {
            const bf16* g = gbase + (size_t)(it + 1) * itstep;
            r0 = *(const int4*)(g + goff[0]);
            r1 = *(const int4*)(g + goff[1]);
            r2 = *(const int4*)(g + goff[2]);
        }

        const short* Kc = Kbuf[cur];
        const short* Vc = Vbuf[cur];

        // --- K fragments (shared by both q-tiles) ---
        short8 kf[6];
        #pragma unroll
        for (int s = 0; s < 6; ++s)
            kf[s] = lds_frag(Kc + col * 100 + s * 16 + hh * 8);

        // --- S^T = K . Q^T for both tiles (independent MFMA chains) ---
        f32x16 stA = (f32x16)(0.f);
        #pragma unroll
        for (int s = 0; s < 6; ++s)
            stA = __builtin_amdgcn_mfma_f32_32x32x16_bf16(kf[s], qfA[s], stA, 0, 0, 0);
        f32x16 stB = (f32x16)(0.f);
        #pragma unroll
        for (int s = 0; s < 6; ++s)
            stB = __builtin_amdgcn_mfma_f32_32x32x16_bf16(kf[s], qfB[s], stB, 0, 0, 0);

        // --- p = exp2(s); pack straight into B-operand frags (A then B,
        //     scoped so pA's f32 temps die before pB's are built) ---
        FU f0A, f1A, f0B, f1B;
        {
            float p[16], ls = 0.f;
            #pragma unroll
            for (int i = 0; i < 16; ++i) { p[i] = fexp2(stA[i]); ls += p[i]; }
            lA += ls;
            #pragma unroll
            for (int j = 0; j < 4; ++j) {
                f0A.w[j] = pk_bf16(p[2 * j],     p[2 * j + 1]);
                f1A.w[j] = pk_bf16(p[8 + 2 * j], p[8 + 2 * j + 1]);
            }
        }
        {
            float p[16], ls = 0.f;
            #pragma unroll
            for (int i = 0; i < 16; ++i) { p[i] = fexp2(stB[i]); ls += p[i]; }
            lB += ls;
            #pragma unroll
            for (int j = 0; j < 4; ++j) {
                f0B.w[j] = pk_bf16(p[2 * j],     p[2 * j + 1]);
                f1B.w[j] = pk_bf16(p[8 + 2 * j], p[8 + 2 * j + 1]);
            }
        }

        // --- O^T += V^T . P^T : vf loaded ONCE, feeds both tiles ---
        #pragma unroll
        for (int t = 0; t < 3; ++t) {
            const short* vr = Vc + (32 * t + col) * 36 + hh * 8;
            short8 vf0 = lds_frag(vr);
            short8 vf1 = lds_frag(vr + 16);
            oaA[t] = __builtin_amdgcn_mfma_f32_32x32x16_bf16(vf0, f0A.v, oaA[t], 0, 0, 0);
            oaA[t] = __builtin_amdgcn_mfma_f32_32x32x16_bf16(vf1, f1A.v, oaA[t], 0, 0, 0);
            oaB[t] = __builtin_amdgcn_mfma_f32_32x32x16_bf16(vf0, f0B.v, oaB[t], 0, 0, 0);
            oaB[t] = __builtin_amdgcn_mfma_f32_32x32x16_bf16(vf1, f1B.v, oaB[t], 0, 0, 0);
        }

        // --- write next tile into the other buffer ---
        if (pre) {
            short* sb = isK ? Kbuf[cur ^ 1] : Vbuf[cur ^ 1];
            *(int2*)(sb + ldsA[0]) = make_int2(r0.x, r0.y);
            *(int2*)(sb + ldsB[0]) = make_int2(r0.z, r0.w);
            *(int2*)(sb + ldsA[1]) = make_int2(r1.x, r1.y);
            *(int2*)(sb + ldsB[1]) = make_int2(r1.z, r1.w);
            *(int2*)(sb + ldsA[2]) = make_int2(r2.x, r2.y);
            *(int2*)(sb + ldsB[2]) = make_int2(r2.z, r2.w);
        }
        __syncthreads();
    }

    // --- epilogue: store unnormalized partial O (bf16) and partial l ---
    {
        size_t bqA = (size_t)b * HW_ + nA;
        size_t bqB = (size_t)b * HW_ + nB;
        float ltA = lA + __shfl_xor(lA, 32, 64);
        float ltB = lB + __shfl_xor(lB, 32, 64);
        if (hh == 0) {
            pl[(size_t)ks * NT_ + bqA] = ltA;
            pl[(size_t)ks * NT_ + bqB] = ltB;
        }
        #pragma unroll
        for (int t = 0; t < 3; ++t)
            #pragma unroll
            for (int g = 0; g < 4; ++g) {
                int c0 = t * 32 + 8 * g + 4 * hh;
                uint2 pkA = make_uint2(
                    pk_bf16(oaA[t][4 * g],     oaA[t][4 * g + 1]),
                    pk_bf16(oaA[t][4 * g + 2], oaA[t][4 * g + 3]));
                *(uint2*)(pob + ((size_t)ks * NT_ + bqA) * C_ + c0) = pkA;
                uint2 pkB = make_uint2(
                    pk_bf16(oaB[t][4 * g],     oaB[t][4 * g + 1]),
                    pk_bf16(oaB[t][4 * g + 2], oaB[t][4 * g + 3]));
                *(uint2*)(pob + ((size_t)ks * NT_ + bqB) * C_ + c0) = pkB;
            }
    }
}

// ---------------------------------------------------------------------------
// Kernel 4: fused merge + output projection + residual.
// Grid = 576 blocks x 256 thr. Coalesced merge of 8 key-split partials into
// an LDS tile (stride 100 -> 2-way banks, free), then waves 0-2 MFMA GEMM.
// ---------------------------------------------------------------------------
__global__ __launch_bounds__(256)
void out_kernel(const float* __restrict__ x,
                const bf16* __restrict__ pob, const float* __restrict__ pl,
                const bf16* __restrict__ wpt, const float* __restrict__ bp,
                float* __restrict__ out) {
    __shared__ short ofs[32 * 100];   // 6.4 KB merged O tile (padded stride)
    __shared__ float linv_s[32];

    int tile = blockIdx.x;            // 0..575
    int n0 = tile * 32;
    int tid = threadIdx.x;

    if (tid < 32) {
        int token = n0 + tid;
        float l = 0.f;
        #pragma unroll
        for (int ksp = 0; ksp < KSPLIT; ++ksp) l += pl[(size_t)ksp * NT_ + token];
        linv_s[tid] = 1.f / l;
    }
    __syncthreads();

    for (int pos = tid; pos < 384; pos += 256) {
        int token = pos / 12, c8 = (pos % 12) * 8;
        float acc[8] = {0.f, 0.f, 0.f, 0.f, 0.f, 0.f, 0.f, 0.f};
        #pragma unroll
        for (int ksp = 0; ksp < KSPLIT; ++ksp) {
            uint4 u = *(const uint4*)(pob + ((size_t)ksp * NT_ + n0 + token) * C_ + c8);
            acc[0] += bl(u.x); acc[1] += bh(u.x);
            acc[2] += bl(u.y); acc[3] += bh(u.y);
            acc[4] += bl(u.z); acc[5] += bh(u.z);
            acc[6] += bl(u.w); acc[7] += bh(u.w);
        }
        float inv = linv_s[token];
        short* dst = ofs + token * 100 + c8;
        *(int2*)(dst)     = make_int2(pk_bf16(acc[0] * inv, acc[1] * inv),
                                      pk_bf16(acc[2] * inv, acc[3] * inv));
        *(int2*)(dst + 4) = make_int2(pk_bf16(acc[4] * inv, acc[5] * inv),
                                      pk_bf16(acc[6] * inv, acc[7] * inv));
    }
    __syncthreads();

    int wave = tid >> 6;
    if (wave >= 3) return;
    int lane = tid & 63, col = lane & 31, hh = lane >> 5;
    int t = wave;
    int token = n0 + col;

    short8 of[6];
    #pragma unroll
    for (int s = 0; s < 6; ++s)
        of[s] = lds_frag(ofs + col * 100 + s * 16 + hh * 8);

    f32x16 acc = (f32x16)(0.f);
    const bf16* wrow = wpt + (size_t)(t * 32 + col) * C_ + hh * 8;
    #pragma unroll
    for (int s = 0; s < 6; ++s)
        acc = __builtin_amdgcn_mfma_f32_32x32x16_bf16(
                *(const short8*)(wrow + s * 16), of[s], acc, 0, 0, 0);
    #pragma unroll
    for (int g = 0; g < 4; ++g) {
        int nb = t * 32 + 8 * g + 4 * hh;
        float4 b4 = *(const float4*)(bp + nb);
        float4 xv = *(const float4*)(x + (size_t)token * C_ + nb);
        float4 rr;
        rr.x = xv.x + acc[4 * g]     + b4.x;
        rr.y = xv.y + acc[4 * g + 1] + b4.y;
        rr.z = xv.z + acc[4 * g + 2] + b4.z;
        rr.w = xv.w + acc[4 * g + 3] + b4.w;
        *(float4*)(out + (size_t)token * C_ + nb) = rr;
    }
}

// ---------------------------------------------------------------------------
extern "C" void kernel_launch(void* const* d_in, const int* in_sizes, int n_in,
                              void* d_out, int out_size, void* d_ws, size_t ws_size,
                              hipStream_t stream) {
    const float* x     = (const float*)d_in[0];
    const float* gamma = (const float*)d_in[1];
    const float* beta  = (const float*)d_in[2];
    const float* Wq    = (const float*)d_in[3];
    const float* bq    = (const float*)d_in[4];
    const float* Wk    = (const float*)d_in[5];
    const float* bk    = (const float*)d_in[6];
    const float* Wv    = (const float*)d_in[7];
    const float* bv    = (const float*)d_in[8];
    const float* Wp    = (const float*)d_in[9];
    const float* bp    = (const float*)d_in[10];
    float* out = (float*)d_out;

    char* ws = (char*)d_ws;
    const size_t TB = (size_t)NT_ * C_ * 2;   // 3.54 MB per bf16 tensor
    bf16* qb  = (bf16*)(ws);
    bf16* kb  = (bf16*)(ws + TB);
    bf16* vt  = (bf16*)(ws + 2 * TB);
    bf16* wqt = (bf16*)(ws + 3 * TB);
    bf16* wkt = (bf16*)(ws + 3 * TB + 18432);
    bf16* wvt = (bf16*)(ws + 3 * TB + 2 * 18432);
    bf16* wpt = (bf16*)(ws + 3 * TB + 3 * 18432);
    float2* stats = (float2*)(ws + 3 * TB + 4 * 18432);
    bf16*  pob = (bf16*)(ws + 3 * TB + 4 * 18432 + 512);          // 28.3 MB
    float* pl  = (float*)(ws + 3 * TB + 4 * 18432 + 512
                          + (size_t)KSPLIT * NT_ * C_ * 2);        // 0.6 MB

    hipLaunchKernelGGL(stats_prep_kernel, dim3(68), dim3(1024), 0, stream,
                       x, stats, Wq, Wk, Wv, Wp, wqt, wkt, wvt, wpt);
    hipLaunchKernelGGL(qkv_kernel, dim3(3 * 576), dim3(64), 0, stream,
                       x, stats, gamma, beta, wqt, wkt, wvt, bq, bk, bv, qb, kb, vt);
    hipLaunchKernelGGL(attn_kernel, dim3(576), dim3(256), 0, stream,
                       qb, kb, vt, pob, pl);
    hipLaunchKernelGGL(out_kernel, dim3(576), dim3(256), 0, stream,
                       x, pob, pl, wpt, bp, out);
}

// Round 5
// 190.123 us; speedup vs baseline: 1.5992x; 1.0219x over previous
//
#include <hip/hip_runtime.h>
#include <hip/hip_bf16.h>
#include <stdint.h>

// Problem constants
#define B_   2
#define H_   96
#define W_   96
#define C_   96
#define HW_  (H_ * W_)       // 9216
#define NT_  (B_ * HW_)      // 18432
#define EPS_ 1e-5f
// softmax scale with log2(e) folded in so native exp2 (v_exp_f32) works
#define SCL (0.10206207261596575f * 1.4426950408889634f)

typedef __hip_bfloat16 bf16;
typedef __attribute__((ext_vector_type(8))) short short8;   // 8 bf16 (MFMA A/B frag)
typedef __attribute__((ext_vector_type(16))) float f32x16;  // MFMA C/D frag

// Fast bf16x2 pack: round-half-up (+0x8000) then v_perm picks the two high
// halves. low16 = bf16(a), high16 = bf16(b).
__device__ __forceinline__ uint32_t pk_bf16(float a, float b) {
    uint32_t ua = __float_as_uint(a) + 0x8000u;
    uint32_t ub = __float_as_uint(b) + 0x8000u;
    return __builtin_amdgcn_perm(ub, ua, 0x07060302u);
}
__device__ __forceinline__ float bl(uint32_t u) { uint32_t x = u << 16;         return *(float*)&x; }
__device__ __forceinline__ float bh(uint32_t u) { uint32_t x = u & 0xffff0000u; return *(float*)&x; }
// raw v_exp_f32 (2-ulp; inputs bounded, result feeds bf16 -> plenty accurate)
__device__ __forceinline__ float fexp2(float x) { return __builtin_amdgcn_exp2f(x); }
// 16B LDS fragment read as 2x ds_read_b64 (8B-aligned; padded strides keep
// bank aliasing at 2-way which is free on gfx950)
__device__ __forceinline__ short8 lds_frag(const short* p) {
    union { int2 h[2]; short8 v; } t;
    t.h[0] = *(const int2*)(p);
    t.h[1] = *(const int2*)(p + 4);
    return t.v;
}

// Rebuild one lane's 48-channel GroupNorm'd fragment set from x + stats.
__device__ __forceinline__ void load_hn_frags(
        const float* __restrict__ x, const float2* __restrict__ stats,
        const float* __restrict__ gamma, const float* __restrict__ beta,
        int token, int hh, short8* hf) {
    int b = token / HW_;
    int h = (token % HW_) / W_;
    float2 st = stats[b * 32 + h / 3];
    float g0 = gamma[h];
    float ga = g0 * st.y;
    float be = beta[h] - st.x * st.y * g0;
    const float* xr = x + (size_t)token * C_ + hh * 8;
    #pragma unroll
    for (int s = 0; s < 6; ++s) {
        float4 a = *(const float4*)(xr + s * 16);
        float4 c = *(const float4*)(xr + s * 16 + 4);
        union { uint32_t w[4]; short8 v; } f;
        f.w[0] = pk_bf16(a.x * ga + be, a.y * ga + be);
        f.w[1] = pk_bf16(a.z * ga + be, a.w * ga + be);
        f.w[2] = pk_bf16(c.x * ga + be, c.y * ga + be);
        f.w[3] = pk_bf16(c.z * ga + be, c.w * ga + be);
        hf[s] = f.v;
    }
}

// ---------------------------------------------------------------------------
// Kernel 1: GroupNorm stats (blocks 0..63, float4 scan + shuffle reduce)
//           + weight transpose (blocks 64..67)
// ---------------------------------------------------------------------------
__global__ __launch_bounds__(1024)
void stats_prep_kernel(const float* __restrict__ x, float2* __restrict__ stats,
                       const float* __restrict__ Wq, const float* __restrict__ Wk,
                       const float* __restrict__ Wv, const float* __restrict__ Wp,
                       bf16* __restrict__ wqt, bf16* __restrict__ wkt,
                       bf16* __restrict__ wvt, bf16* __restrict__ wpt) {
    int blk = blockIdx.x;
    int tid = threadIdx.x;
    if (blk >= 64) {
        int wsel = blk - 64;
        const float* S = (wsel == 0) ? Wq : (wsel == 1) ? Wk : (wsel == 2) ? Wv : Wp;
        bf16* D = (wsel == 0) ? wqt : (wsel == 1) ? wkt : (wsel == 2) ? wvt : wpt;
        for (int i = tid; i < C_ * C_; i += 1024) {
            int r = i / C_, c = i % C_;
            D[c * C_ + r] = __float2bfloat16(S[r * C_ + c]);
        }
        return;
    }
    int b = blk >> 5, g = blk & 31;
    const int n4 = 3 * W_ * C_ / 4;   // 6912 float4s
    const float4* xb = (const float4*)(x + (size_t)(b * H_ + 3 * g) * (W_ * C_));
    float s = 0.f, ss = 0.f;
    for (int i = tid; i < n4; i += 1024) {
        float4 v = xb[i];
        s  += v.x + v.y + v.z + v.w;
        ss += v.x * v.x + v.y * v.y + v.z * v.z + v.w * v.w;
    }
    // wave shuffle reduce
    #pragma unroll
    for (int off = 1; off < 64; off <<= 1) {
        s  += __shfl_xor(s, off, 64);
        ss += __shfl_xor(ss, off, 64);
    }
    __shared__ float rs[16], rss[16];
    int wid = tid >> 6;
    if ((tid & 63) == 0) { rs[wid] = s; rss[wid] = ss; }
    __syncthreads();
    if (tid == 0) {
        float ts = 0.f, tss = 0.f;
        #pragma unroll
        for (int i = 0; i < 16; ++i) { ts += rs[i]; tss += rss[i]; }
        const float n = 3 * W_ * C_;
        float mean = ts / n;
        float var  = tss / n - mean * mean;
        stats[blk] = make_float2(mean, rsqrtf(var + EPS_));
    }
}

// ---------------------------------------------------------------------------
// Kernel 2: fused GroupNorm-apply + QKV projection via MFMA.
// Grid = 3 * 576 ONE-WAVE blocks (6.75 blocks/CU -> fast ramp; measured
// ~4 us better than 4-wave blocks in R14).
// ---------------------------------------------------------------------------
__global__ __launch_bounds__(64)
void qkv_kernel(const float* __restrict__ x, const float2* __restrict__ stats,
                const float* __restrict__ gamma, const float* __restrict__ beta,
                const bf16* __restrict__ wqt, const bf16* __restrict__ wkt,
                const bf16* __restrict__ wvt,
                const float* __restrict__ bq, const float* __restrict__ bk,
                const float* __restrict__ bv,
                bf16* __restrict__ qb, bf16* __restrict__ kb, bf16* __restrict__ vt) {
    int blk = blockIdx.x;
    int w = blk / 576, tile = blk % 576;
    int n0 = tile * 32;
    int lane = threadIdx.x;
    int col = lane & 31, hh = lane >> 5;
    int token = n0 + col;

    short8 hf[6];
    load_hn_frags(x, stats, gamma, beta, token, hh, hf);

    if (w == 2) {
        int bb = n0 / HW_, nl0 = n0 % HW_;
        #pragma unroll
        for (int t = 0; t < 3; ++t) {
            int c = t * 32 + col;
            const bf16* wrow = wvt + (size_t)c * C_ + hh * 8;
            f32x16 acc = (f32x16)(0.f);
            #pragma unroll
            for (int s = 0; s < 6; ++s)
                acc = __builtin_amdgcn_mfma_f32_32x32x16_bf16(
                        hf[s], *(const short8*)(wrow + s * 16), acc, 0, 0, 0);
            float bias = bv[c];
            bf16* dst = vt + ((size_t)bb * C_ + c) * HW_ + nl0 + 4 * hh;
            #pragma unroll
            for (int g = 0; g < 4; ++g) {
                uint2 pk = make_uint2(pk_bf16(acc[4 * g] + bias, acc[4 * g + 1] + bias),
                                      pk_bf16(acc[4 * g + 2] + bias, acc[4 * g + 3] + bias));
                *(uint2*)(dst + 8 * g) = pk;
            }
        }
    } else {
        const bf16*  wt   = (w == 0) ? wqt : wkt;
        const float* bias = (w == 0) ? bq : bk;
        bf16*        dst  = (w == 0) ? qb : kb;
        float        scl  = (w == 0) ? SCL : 1.f;
        #pragma unroll
        for (int t = 0; t < 3; ++t) {
            const bf16* wrow = wt + (size_t)(t * 32 + col) * C_ + hh * 8;
            f32x16 acc = (f32x16)(0.f);
            #pragma unroll
            for (int s = 0; s < 6; ++s)
                acc = __builtin_amdgcn_mfma_f32_32x32x16_bf16(
                        *(const short8*)(wrow + s * 16), hf[s], acc, 0, 0, 0);
            #pragma unroll
            for (int g = 0; g < 4; ++g) {
                int nb = t * 32 + 8 * g + 4 * hh;
                float4 b4 = *(const float4*)(bias + nb);
                float v0 = (acc[4 * g]     + b4.x) * scl;
                float v1 = (acc[4 * g + 1] + b4.y) * scl;
                float v2 = (acc[4 * g + 2] + b4.z) * scl;
                float v3 = (acc[4 * g + 3] + b4.w) * scl;
                uint2 pk = make_uint2(pk_bf16(v0, v1), pk_bf16(v2, v3));
                *(uint2*)(dst + (size_t)token * C_ + nb) = pk;
            }
        }
    }
}

// ---------------------------------------------------------------------------
// Kernel 3: MFMA flash attention, dual-Q per wave, KSPLIT templated (R18).
// R17 post-mortem: dual-Q halved LDS traffic (bank-conflict counter halved,
// no spill) but also halved TLP (grid 1152->576, 2.25 waves/SIMD) -- duration
// flat at 94.7us because the kernel is LATENCY-bound (issue util ~58%, waves
// stalled ~80% of cycles) and stalls are hidden only by TLP.
// R18: keep the R17 loop body BYTE-IDENTICAL (proven spill-free), restore
// TLP by doubling the key-split: KSPLIT 8 -> 16 => grid 1152 (4.5 blocks/CU,
// 18 waves/CU), ATT_NIT 18. LDS per cycle stays at R17's relaxed level.
// Runtime fallback to KSPLIT=8 if workspace is too small for 16 partials.
// ---------------------------------------------------------------------------
template<int KS, int LOG2KS>
__global__ __launch_bounds__(256, 2)
void attn_kernel(const bf16* __restrict__ qb, const bf16* __restrict__ kb,
                 const bf16* __restrict__ vt,
                 bf16* __restrict__ pob, float* __restrict__ pl) {
    constexpr int KRANGE  = HW_ / KS;     // keys per block
    constexpr int ATT_NIT = KRANGE / 32;  // iterations

    __shared__ short Kbuf[2][32 * 100];   // 12.8 KB
    __shared__ short Vbuf[2][96 * 36];    // 13.8 KB

    int blk = blockIdx.x;
    int ks = blk & (KS - 1), qg = blk >> LOG2KS;   // qg 0..71
    int b = qg / 36, g36 = qg % 36;
    int n0 = g36 * 256;                    // 256 q-rows per block
    int tid = threadIdx.x;
    int wave = tid >> 6, lane = tid & 63;
    int col = lane & 31, hh = lane >> 5;

    const bf16* kbb = kb + ((size_t)b * HW_ + (size_t)ks * KRANGE) * C_;
    const bf16* vbb = vt + (size_t)b * C_ * HW_ + (size_t)ks * KRANGE;

    // --- persistent Q fragments: TWO 32-row tiles per wave (A: wave*32,
    //     B: wave*32+128) ---
    int nA = n0 + wave * 32 + col;
    int nB = nA + 128;
    short8 qfA[6], qfB[6];
    {
        const bf16* qrowA = qb + (size_t)(b * HW_ + nA) * C_ + hh * 8;
        const bf16* qrowB = qb + (size_t)(b * HW_ + nB) * C_ + hh * 8;
        #pragma unroll
        for (int s = 0; s < 6; ++s) qfA[s] = *(const short8*)(qrowA + s * 16);
        #pragma unroll
        for (int s = 0; s < 6; ++s) qfB[s] = *(const short8*)(qrowB + s * 16);
    }

    f32x16 oaA[3], oaB[3];
    #pragma unroll
    for (int t = 0; t < 3; ++t) { oaA[t] = (f32x16)(0.f); oaB[t] = (f32x16)(0.f); }
    float lA = 0.f, lB = 0.f;

    // --- staging geometry: threads 0..127 stage K (384 16B-chunks),
    //     threads 128..255 stage V (384 chunks, permuted columns) ---
    bool isK = (tid < 128);
    int t128 = tid & 127;
    int ldsA[3], ldsB[3], goff[3];
    #pragma unroll
    for (int j = 0; j < 3; ++j) {
        int c = t128 + 128 * j;
        if (isK) {
            ldsA[j] = (c / 12) * 100 + (c % 12) * 8;
            ldsB[j] = ldsA[j] + 4;
            goff[j] = c * 8;
        } else {
            int rw = c >> 2, g = c & 3;
            // V permutation: key-group 2g -> pos-group 2g-(g&1); 2g+1 -> 2g+2-(g&1)
            ldsA[j] = rw * 36 + (2 * g - (g & 1)) * 4;
            ldsB[j] = rw * 36 + (2 * g + 2 - (g & 1)) * 4;
            goff[j] = rw * HW_ + g * 8;
        }
    }
    const bf16* gbase = isK ? kbb : vbb;
    const int itstep = isK ? (32 * C_) : 32;

    // --- prologue: stage tile 0 into buffer 0 ---
    {
        short* sb = isK ? Kbuf[0] : Vbuf[0];
        #pragma unroll
        for (int j = 0; j < 3; ++j) {
            int4 r = *(const int4*)(gbase + goff[j]);
            *(int2*)(sb + ldsA[j]) = make_int2(r.x, r.y);
            *(int2*)(sb + ldsB[j]) = make_int2(r.z, r.w);
        }
    }
    __syncthreads();

    union FU { uint32_t w[4]; short8 v; };

    for (int it = 0; it < ATT_NIT; ++it) {
        int cur = it & 1;
        bool pre = (it + 1 < ATT_NIT);
        int4 r0, r1, r2;
        if (pre) {
            const bf16* g = gbase + (size_t)(it + 1) * itstep;
            r0 = *(const int4*)(g + goff[0]);
            r1 = *(const int4*)(g + goff[1]);
            r2 = *(const int4*)(g + goff[2]);
        }

        const short* Kc = Kbuf[cur];
        const short* Vc = Vbuf[cur];

        // --- K fragments (shared by both q-tiles) ---
        short8 kf[6];
        #pragma unroll
        for (int s = 0; s < 6; ++s)
            kf[s] = lds_frag(Kc + col * 100 + s * 16 + hh * 8);

        // --- S^T = K . Q^T for both tiles (independent MFMA chains) ---
        f32x16 stA = (f32x16)(0.f);
        #pragma unroll
        for (int s = 0; s < 6; ++s)
            stA = __builtin_amdgcn_mfma_f32_32x32x16_bf16(kf[s], qfA[s], stA, 0, 0, 0);
        f32x16 stB = (f32x16)(0.f);
        #pragma unroll
        for (int s = 0; s < 6; ++s)
            stB = __builtin_amdgcn_mfma_f32_32x32x16_bf16(kf[s], qfB[s], stB, 0, 0, 0);

        // --- p = exp2(s); pack straight into B-operand frags (A then B,
        //     scoped so pA's f32 temps die before pB's are built) ---
        FU f0A, f1A, f0B, f1B;
        {
            float p[16], ls = 0.f;
            #pragma unroll
            for (int i = 0; i < 16; ++i) { p[i] = fexp2(stA[i]); ls += p[i]; }
            lA += ls;
            #pragma unroll
            for (int j = 0; j < 4; ++j) {
                f0A.w[j] = pk_bf16(p[2 * j],     p[2 * j + 1]);
                f1A.w[j] = pk_bf16(p[8 + 2 * j], p[8 + 2 * j + 1]);
            }
        }
        {
            float p[16], ls = 0.f;
            #pragma unroll
            for (int i = 0; i < 16; ++i) { p[i] = fexp2(stB[i]); ls += p[i]; }
            lB += ls;
            #pragma unroll
            for (int j = 0; j < 4; ++j) {
                f0B.w[j] = pk_bf16(p[2 * j],     p[2 * j + 1]);
                f1B.w[j] = pk_bf16(p[8 + 2 * j], p[8 + 2 * j + 1]);
            }
        }

        // --- O^T += V^T . P^T : vf loaded ONCE, feeds both tiles ---
        #pragma unroll
        for (int t = 0; t < 3; ++t) {
            const short* vr = Vc + (32 * t + col) * 36 + hh * 8;
            short8 vf0 = lds_frag(vr);
            short8 vf1 = lds_frag(vr + 16);
            oaA[t] = __builtin_amdgcn_mfma_f32_32x32x16_bf16(vf0, f0A.v, oaA[t], 0, 0, 0);
            oaA[t] = __builtin_amdgcn_mfma_f32_32x32x16_bf16(vf1, f1A.v, oaA[t], 0, 0, 0);
            oaB[t] = __builtin_amdgcn_mfma_f32_32x32x16_bf16(vf0, f0B.v, oaB[t], 0, 0, 0);
            oaB[t] = __builtin_amdgcn_mfma_f32_32x32x16_bf16(vf1, f1B.v, oaB[t], 0, 0, 0);
        }

        // --- write next tile into the other buffer ---
        if (pre) {
            short* sb = isK ? Kbuf[cur ^ 1] : Vbuf[cur ^ 1];
            *(int2*)(sb + ldsA[0]) = make_int2(r0.x, r0.y);
            *(int2*)(sb + ldsB[0]) = make_int2(r0.z, r0.w);
            *(int2*)(sb + ldsA[1]) = make_int2(r1.x, r1.y);
            *(int2*)(sb + ldsB[1]) = make_int2(r1.z, r1.w);
            *(int2*)(sb + ldsA[2]) = make_int2(r2.x, r2.y);
            *(int2*)(sb + ldsB[2]) = make_int2(r2.z, r2.w);
        }
        __syncthreads();
    }

    // --- epilogue: store unnormalized partial O (bf16) and partial l ---
    {
        size_t bqA = (size_t)b * HW_ + nA;
        size_t bqB = (size_t)b * HW_ + nB;
        float ltA = lA + __shfl_xor(lA, 32, 64);
        float ltB = lB + __shfl_xor(lB, 32, 64);
        if (hh == 0) {
            pl[(size_t)ks * NT_ + bqA] = ltA;
            pl[(size_t)ks * NT_ + bqB] = ltB;
        }
        #pragma unroll
        for (int t = 0; t < 3; ++t)
            #pragma unroll
            for (int g = 0; g < 4; ++g) {
                int c0 = t * 32 + 8 * g + 4 * hh;
                uint2 pkA = make_uint2(
                    pk_bf16(oaA[t][4 * g],     oaA[t][4 * g + 1]),
                    pk_bf16(oaA[t][4 * g + 2], oaA[t][4 * g + 3]));
                *(uint2*)(pob + ((size_t)ks * NT_ + bqA) * C_ + c0) = pkA;
                uint2 pkB = make_uint2(
                    pk_bf16(oaB[t][4 * g],     oaB[t][4 * g + 1]),
                    pk_bf16(oaB[t][4 * g + 2], oaB[t][4 * g + 3]));
                *(uint2*)(pob + ((size_t)ks * NT_ + bqB) * C_ + c0) = pkB;
            }
    }
}

// ---------------------------------------------------------------------------
// Kernel 4: fused merge + output projection + residual (KSPLIT templated).
// Grid = 576 blocks x 256 thr. Coalesced merge of KS key-split partials into
// an LDS tile (stride 100 -> 2-way banks, free), then waves 0-2 MFMA GEMM.
// ---------------------------------------------------------------------------
template<int KS>
__global__ __launch_bounds__(256)
void out_kernel(const float* __restrict__ x,
                const bf16* __restrict__ pob, const float* __restrict__ pl,
                const bf16* __restrict__ wpt, const float* __restrict__ bp,
                float* __restrict__ out) {
    __shared__ short ofs[32 * 100];   // 6.4 KB merged O tile (padded stride)
    __shared__ float linv_s[32];

    int tile = blockIdx.x;            // 0..575
    int n0 = tile * 32;
    int tid = threadIdx.x;

    if (tid < 32) {
        int token = n0 + tid;
        float l = 0.f;
        #pragma unroll
        for (int ksp = 0; ksp < KS; ++ksp) l += pl[(size_t)ksp * NT_ + token];
        linv_s[tid] = 1.f / l;
    }
    __syncthreads();

    for (int pos = tid; pos < 384; pos += 256) {
        int token = pos / 12, c8 = (pos % 12) * 8;
        float acc[8] = {0.f, 0.f, 0.f, 0.f, 0.f, 0.f, 0.f, 0.f};
        #pragma unroll
        for (int ksp = 0; ksp < KS; ++ksp) {
            uint4 u = *(const uint4*)(pob + ((size_t)ksp * NT_ + n0 + token) * C_ + c8);
            acc[0] += bl(u.x); acc[1] += bh(u.x);
            acc[2] += bl(u.y); acc[3] += bh(u.y);
            acc[4] += bl(u.z); acc[5] += bh(u.z);
            acc[6] += bl(u.w); acc[7] += bh(u.w);
        }
        float inv = linv_s[token];
        short* dst = ofs + token * 100 + c8;
        *(int2*)(dst)     = make_int2(pk_bf16(acc[0] * inv, acc[1] * inv),
                                      pk_bf16(acc[2] * inv, acc[3] * inv));
        *(int2*)(dst + 4) = make_int2(pk_bf16(acc[4] * inv, acc[5] * inv),
                                      pk_bf16(acc[6] * inv, acc[7] * inv));
    }
    __syncthreads();

    int wave = tid >> 6;
    if (wave >= 3) return;
    int lane = tid & 63, col = lane & 31, hh = lane >> 5;
    int t = wave;
    int token = n0 + col;

    short8 of[6];
    #pragma unroll
    for (int s = 0; s < 6; ++s)
        of[s] = lds_frag(ofs + col * 100 + s * 16 + hh * 8);

    f32x16 acc = (f32x16)(0.f);
    const bf16* wrow = wpt + (size_t)(t * 32 + col) * C_ + hh * 8;
    #pragma unroll
    for (int s = 0; s < 6; ++s)
        acc = __builtin_amdgcn_mfma_f32_32x32x16_bf16(
                *(const short8*)(wrow + s * 16), of[s], acc, 0, 0, 0);
    #pragma unroll
    for (int g = 0; g < 4; ++g) {
        int nb = t * 32 + 8 * g + 4 * hh;
        float4 b4 = *(const float4*)(bp + nb);
        float4 xv = *(const float4*)(x + (size_t)token * C_ + nb);
        float4 rr;
        rr.x = xv.x + acc[4 * g]     + b4.x;
        rr.y = xv.y + acc[4 * g + 1] + b4.y;
        rr.z = xv.z + acc[4 * g + 2] + b4.z;
        rr.w = xv.w + acc[4 * g + 3] + b4.w;
        *(float4*)(out + (size_t)token * C_ + nb) = rr;
    }
}

// ---------------------------------------------------------------------------
extern "C" void kernel_launch(void* const* d_in, const int* in_sizes, int n_in,
                              void* d_out, int out_size, void* d_ws, size_t ws_size,
                              hipStream_t stream) {
    const float* x     = (const float*)d_in[0];
    const float* gamma = (const float*)d_in[1];
    const float* beta  = (const float*)d_in[2];
    const float* Wq    = (const float*)d_in[3];
    const float* bq    = (const float*)d_in[4];
    const float* Wk    = (const float*)d_in[5];
    const float* bk    = (const float*)d_in[6];
    const float* Wv    = (const float*)d_in[7];
    const float* bv    = (const float*)d_in[8];
    const float* Wp    = (const float*)d_in[9];
    const float* bp    = (const float*)d_in[10];
    float* out = (float*)d_out;

    char* ws = (char*)d_ws;
    const size_t TB = (size_t)NT_ * C_ * 2;   // 3.54 MB per bf16 tensor
    bf16* qb  = (bf16*)(ws);
    bf16* kb  = (bf16*)(ws + TB);
    bf16* vt  = (bf16*)(ws + 2 * TB);
    bf16* wqt = (bf16*)(ws + 3 * TB);
    bf16* wkt = (bf16*)(ws + 3 * TB + 18432);
    bf16* wvt = (bf16*)(ws + 3 * TB + 2 * 18432);
    bf16* wpt = (bf16*)(ws + 3 * TB + 3 * 18432);
    float2* stats = (float2*)(ws + 3 * TB + 4 * 18432);
    bf16*  pob = (bf16*)(ws + 3 * TB + 4 * 18432 + 512);

    hipLaunchKernelGGL(stats_prep_kernel, dim3(68), dim3(1024), 0, stream,
                       x, stats, Wq, Wk, Wv, Wp, wqt, wkt, wvt, wpt);
    hipLaunchKernelGGL(qkv_kernel, dim3(3 * 576), dim3(64), 0, stream,
                       x, stats, gamma, beta, wqt, wkt, wvt, bq, bk, bv, qb, kb, vt);

    const size_t base   = 3 * TB + 4 * 18432 + 512;
    const size_t need16 = base + (size_t)16 * NT_ * C_ * 2 + (size_t)16 * NT_ * 4;
    if (ws_size >= need16) {
        float* pl = (float*)(ws + base + (size_t)16 * NT_ * C_ * 2);
        hipLaunchKernelGGL((attn_kernel<16, 4>), dim3(16 * 72), dim3(256), 0, stream,
                           qb, kb, vt, pob, pl);
        hipLaunchKernelGGL((out_kernel<16>), dim3(576), dim3(256), 0, stream,
                           x, pob, pl, wpt, bp, out);
    } else {
        float* pl = (float*)(ws + base + (size_t)8 * NT_ * C_ * 2);
        hipLaunchKernelGGL((attn_kernel<8, 3>), dim3(8 * 72), dim3(256), 0, stream,
                           qb, kb, vt, pob, pl);
        hipLaunchKernelGGL((out_kernel<8>), dim3(576), dim3(256), 0, stream,
                           x, pob, pl, wpt, bp, out);
    }
}

// Round 6
// 189.680 us; speedup vs baseline: 1.6030x; 1.0023x over previous
//
#include <hip/hip_runtime.h>
#include <hip/hip_bf16.h>
#include <stdint.h>

// Problem constants
#define B_   2
#define H_   96
#define W_   96
#define C_   96
#define HW_  (H_ * W_)       // 9216
#define NT_  (B_ * HW_)      // 18432
#define EPS_ 1e-5f
// softmax scale with log2(e) folded in so native exp2 (v_exp_f32) works
#define SCL (0.10206207261596575f * 1.4426950408889634f)

typedef __hip_bfloat16 bf16;
typedef __attribute__((ext_vector_type(8))) short short8;   // 8 bf16 (MFMA A/B frag)
typedef __attribute__((ext_vector_type(16))) float f32x16;  // MFMA C/D frag

// Fast bf16x2 pack: round-half-up (+0x8000) then v_perm picks the two high
// halves. low16 = bf16(a), high16 = bf16(b).
__device__ __forceinline__ uint32_t pk_bf16(float a, float b) {
    uint32_t ua = __float_as_uint(a) + 0x8000u;
    uint32_t ub = __float_as_uint(b) + 0x8000u;
    return __builtin_amdgcn_perm(ub, ua, 0x07060302u);
}
__device__ __forceinline__ float bl(uint32_t u) { uint32_t x = u << 16;         return *(float*)&x; }
__device__ __forceinline__ float bh(uint32_t u) { uint32_t x = u & 0xffff0000u; return *(float*)&x; }
// raw v_exp_f32 (2-ulp; inputs bounded, result feeds bf16 -> plenty accurate)
__device__ __forceinline__ float fexp2(float x) { return __builtin_amdgcn_exp2f(x); }
// 16B LDS fragment read as 2x ds_read_b64 (8B-aligned; padded strides keep
// bank aliasing at 2-way which is free on gfx950)
__device__ __forceinline__ short8 lds_frag(const short* p) {
    union { int2 h[2]; short8 v; } t;
    t.h[0] = *(const int2*)(p);
    t.h[1] = *(const int2*)(p + 4);
    return t.v;
}

// Rebuild one lane's 48-channel GroupNorm'd fragment set from x + stats.
__device__ __forceinline__ void load_hn_frags(
        const float* __restrict__ x, const float2* __restrict__ stats,
        const float* __restrict__ gamma, const float* __restrict__ beta,
        int token, int hh, short8* hf) {
    int b = token / HW_;
    int h = (token % HW_) / W_;
    float2 st = stats[b * 32 + h / 3];
    float g0 = gamma[h];
    float ga = g0 * st.y;
    float be = beta[h] - st.x * st.y * g0;
    const float* xr = x + (size_t)token * C_ + hh * 8;
    #pragma unroll
    for (int s = 0; s < 6; ++s) {
        float4 a = *(const float4*)(xr + s * 16);
        float4 c = *(const float4*)(xr + s * 16 + 4);
        union { uint32_t w[4]; short8 v; } f;
        f.w[0] = pk_bf16(a.x * ga + be, a.y * ga + be);
        f.w[1] = pk_bf16(a.z * ga + be, a.w * ga + be);
        f.w[2] = pk_bf16(c.x * ga + be, c.y * ga + be);
        f.w[3] = pk_bf16(c.z * ga + be, c.w * ga + be);
        hf[s] = f.v;
    }
}

// ---------------------------------------------------------------------------
// Kernel 1: GroupNorm stats (blocks 0..63, float4 scan + shuffle reduce)
//           + weight transpose (blocks 64..67)
// ---------------------------------------------------------------------------
__global__ __launch_bounds__(1024)
void stats_prep_kernel(const float* __restrict__ x, float2* __restrict__ stats,
                       const float* __restrict__ Wq, const float* __restrict__ Wk,
                       const float* __restrict__ Wv, const float* __restrict__ Wp,
                       bf16* __restrict__ wqt, bf16* __restrict__ wkt,
                       bf16* __restrict__ wvt, bf16* __restrict__ wpt) {
    int blk = blockIdx.x;
    int tid = threadIdx.x;
    if (blk >= 64) {
        int wsel = blk - 64;
        const float* S = (wsel == 0) ? Wq : (wsel == 1) ? Wk : (wsel == 2) ? Wv : Wp;
        bf16* D = (wsel == 0) ? wqt : (wsel == 1) ? wkt : (wsel == 2) ? wvt : wpt;
        for (int i = tid; i < C_ * C_; i += 1024) {
            int r = i / C_, c = i % C_;
            D[c * C_ + r] = __float2bfloat16(S[r * C_ + c]);
        }
        return;
    }
    int b = blk >> 5, g = blk & 31;
    const int n4 = 3 * W_ * C_ / 4;   // 6912 float4s
    const float4* xb = (const float4*)(x + (size_t)(b * H_ + 3 * g) * (W_ * C_));
    float s = 0.f, ss = 0.f;
    for (int i = tid; i < n4; i += 1024) {
        float4 v = xb[i];
        s  += v.x + v.y + v.z + v.w;
        ss += v.x * v.x + v.y * v.y + v.z * v.z + v.w * v.w;
    }
    // wave shuffle reduce
    #pragma unroll
    for (int off = 1; off < 64; off <<= 1) {
        s  += __shfl_xor(s, off, 64);
        ss += __shfl_xor(ss, off, 64);
    }
    __shared__ float rs[16], rss[16];
    int wid = tid >> 6;
    if ((tid & 63) == 0) { rs[wid] = s; rss[wid] = ss; }
    __syncthreads();
    if (tid == 0) {
        float ts = 0.f, tss = 0.f;
        #pragma unroll
        for (int i = 0; i < 16; ++i) { ts += rs[i]; tss += rss[i]; }
        const float n = 3 * W_ * C_;
        float mean = ts / n;
        float var  = tss / n - mean * mean;
        stats[blk] = make_float2(mean, rsqrtf(var + EPS_));
    }
}

// ---------------------------------------------------------------------------
// Kernel 2: fused GroupNorm-apply + QKV projection via MFMA (R19).
// Grid = 3 * 576 ONE-WAVE blocks.
// R19 CHANGE: the old epilogue issued 8B stores per lane at 192B (q/k) or
// 18KB (vt) lane stride -> 64 partially-used cache lines per store instr
// (~4-8x write amplification on 10.6 MB, unhidden at 1.7 waves/SIMD).
// Now: MFMA results bounce through a 6.9 KB LDS tile, then stream out with
// a lane->linear mapping: q/k writes are fully contiguous (1 KB/instr);
// vt writes are 16 FULLY-written 64B lines/instr. Identical arithmetic.
// ---------------------------------------------------------------------------
__global__ __launch_bounds__(64)
void qkv_kernel(const float* __restrict__ x, const float2* __restrict__ stats,
                const float* __restrict__ gamma, const float* __restrict__ beta,
                const bf16* __restrict__ wqt, const bf16* __restrict__ wkt,
                const bf16* __restrict__ wvt,
                const float* __restrict__ bq, const float* __restrict__ bk,
                const float* __restrict__ bv,
                bf16* __restrict__ qb, bf16* __restrict__ kb, bf16* __restrict__ vt) {
    __shared__ short tile_s[96 * 36];   // 6.9 KB; q/k path uses first 3200

    int blk = blockIdx.x;
    int w = blk / 576, tile = blk % 576;
    int n0 = tile * 32;
    int lane = threadIdx.x;
    int col = lane & 31, hh = lane >> 5;
    int token = n0 + col;

    short8 hf[6];
    load_hn_frags(x, stats, gamma, beta, token, hh, hf);

    if (w == 2) {
        int bb = n0 / HW_, nl0 = n0 % HW_;
        #pragma unroll
        for (int t = 0; t < 3; ++t) {
            int c = t * 32 + col;
            const bf16* wrow = wvt + (size_t)c * C_ + hh * 8;
            f32x16 acc = (f32x16)(0.f);
            #pragma unroll
            for (int s = 0; s < 6; ++s)
                acc = __builtin_amdgcn_mfma_f32_32x32x16_bf16(
                        hf[s], *(const short8*)(wrow + s * 16), acc, 0, 0, 0);
            float bias = bv[c];
            // LDS tile: [96 ch][36 tok-pad] (stride 36 shorts = 18 dwords,
            // gcd(18,32)=2 -> 2-way banks, free). Lane owns channel c,
            // tokens 4hh+8g+{0..3}.
            short* dst = tile_s + c * 36 + 4 * hh;
            #pragma unroll
            for (int g = 0; g < 4; ++g) {
                int2 pk = make_int2(pk_bf16(acc[4 * g] + bias, acc[4 * g + 1] + bias),
                                    pk_bf16(acc[4 * g + 2] + bias, acc[4 * g + 3] + bias));
                *(int2*)(dst + 8 * g) = pk;
            }
        }
        __syncthreads();
        // coalesced writeback: 96 ch x 32 tok; per instr 64 lanes cover 16
        // channels x full 64B lines.
        bf16* vbase = vt + (size_t)bb * C_ * HW_ + nl0;
        #pragma unroll
        for (int i = 0; i < 6; ++i) {
            int pos = lane + 64 * i;            // 0..383
            int ch = pos >> 2, q4 = pos & 3;    // 16B chunk = 8 tokens
            short8 vv = lds_frag(tile_s + ch * 36 + q4 * 8);
            *(short8*)(vbase + (size_t)ch * HW_ + q4 * 8) = vv;
        }
    } else {
        const bf16*  wt   = (w == 0) ? wqt : wkt;
        const float* bias = (w == 0) ? bq : bk;
        bf16*        dst  = (w == 0) ? qb : kb;
        float        scl  = (w == 0) ? SCL : 1.f;
        #pragma unroll
        for (int t = 0; t < 3; ++t) {
            const bf16* wrow = wt + (size_t)(t * 32 + col) * C_ + hh * 8;
            f32x16 acc = (f32x16)(0.f);
            #pragma unroll
            for (int s = 0; s < 6; ++s)
                acc = __builtin_amdgcn_mfma_f32_32x32x16_bf16(
                        *(const short8*)(wrow + s * 16), hf[s], acc, 0, 0, 0);
            #pragma unroll
            for (int g = 0; g < 4; ++g) {
                int nb = t * 32 + 8 * g + 4 * hh;
                float4 b4 = *(const float4*)(bias + nb);
                float v0 = (acc[4 * g]     + b4.x) * scl;
                float v1 = (acc[4 * g + 1] + b4.y) * scl;
                float v2 = (acc[4 * g + 2] + b4.z) * scl;
                float v3 = (acc[4 * g + 3] + b4.w) * scl;
                // LDS tile: [32 tok][100 ch-pad] (stride 100 shorts = 50
                // dwords, gcd(50,32)=2 -> 2-way banks, free).
                *(int2*)(tile_s + col * 100 + nb) =
                    make_int2(pk_bf16(v0, v1), pk_bf16(v2, v3));
            }
        }
        __syncthreads();
        // coalesced writeback: rows are 192B; lane->linear mapping makes
        // each store instr a fully-contiguous 1KB span.
        bf16* dbase = dst + (size_t)n0 * C_;
        #pragma unroll
        for (int i = 0; i < 6; ++i) {
            int pos = lane + 64 * i;            // 0..383
            int tok = pos / 12, ch8 = (pos % 12) * 8;
            short8 vv = lds_frag(tile_s + tok * 100 + ch8);
            *(short8*)(dbase + tok * C_ + ch8) = vv;
        }
    }
}

// ---------------------------------------------------------------------------
// Kernel 3: MFMA flash attention, dual-Q per wave, KSPLIT templated (R18 —
// FROZEN this round).
// R18 post-mortem: dual-Q costs ~224 unified regs/thread -> 2 waves/SIMD;
// KS=16 trimmed the tail (94.7 -> 86.5 us) but resident TLP is reg-capped.
// Attn sits at a reg-budget/LDS-traffic equilibrium; left unchanged while
// qkv's write path is the experiment.
// ---------------------------------------------------------------------------
template<int KS, int LOG2KS>
__global__ __launch_bounds__(256, 2)
void attn_kernel(const bf16* __restrict__ qb, const bf16* __restrict__ kb,
                 const bf16* __restrict__ vt,
                 bf16* __restrict__ pob, float* __restrict__ pl) {
    constexpr int KRANGE  = HW_ / KS;     // keys per block
    constexpr int ATT_NIT = KRANGE / 32;  // iterations

    __shared__ short Kbuf[2][32 * 100];   // 12.8 KB
    __shared__ short Vbuf[2][96 * 36];    // 13.8 KB

    int blk = blockIdx.x;
    int ks = blk & (KS - 1), qg = blk >> LOG2KS;   // qg 0..71
    int b = qg / 36, g36 = qg % 36;
    int n0 = g36 * 256;                    // 256 q-rows per block
    int tid = threadIdx.x;
    int wave = tid >> 6, lane = tid & 63;
    int col = lane & 31, hh = lane >> 5;

    const bf16* kbb = kb + ((size_t)b * HW_ + (size_t)ks * KRANGE) * C_;
    const bf16* vbb = vt + (size_t)b * C_ * HW_ + (size_t)ks * KRANGE;

    // --- persistent Q fragments: TWO 32-row tiles per wave (A: wave*32,
    //     B: wave*32+128) ---
    int nA = n0 + wave * 32 + col;
    int nB = nA + 128;
    short8 qfA[6], qfB[6];
    {
        const bf16* qrowA = qb + (size_t)(b * HW_ + nA) * C_ + hh * 8;
        const bf16* qrowB = qb + (size_t)(b * HW_ + nB) * C_ + hh * 8;
        #pragma unroll
        for (int s = 0; s < 6; ++s) qfA[s] = *(const short8*)(qrowA + s * 16);
        #pragma unroll
        for (int s = 0; s < 6; ++s) qfB[s] = *(const short8*)(qrowB + s * 16);
    }

    f32x16 oaA[3], oaB[3];
    #pragma unroll
    for (int t = 0; t < 3; ++t) { oaA[t] = (f32x16)(0.f); oaB[t] = (f32x16)(0.f); }
    float lA = 0.f, lB = 0.f;

    // --- staging geometry: threads 0..127 stage K (384 16B-chunks),
    //     threads 128..255 stage V (384 chunks, permuted columns) ---
    bool isK = (tid < 128);
    int t128 = tid & 127;
    int ldsA[3], ldsB[3], goff[3];
    #pragma unroll
    for (int j = 0; j < 3; ++j) {
        int c = t128 + 128 * j;
        if (isK) {
            ldsA[j] = (c / 12) * 100 + (c % 12) * 8;
            ldsB[j] = ldsA[j] + 4;
            goff[j] = c * 8;
        } else {
            int rw = c >> 2, g = c & 3;
            // V permutation: key-group 2g -> pos-group 2g-(g&1); 2g+1 -> 2g+2-(g&1)
            ldsA[j] = rw * 36 + (2 * g - (g & 1)) * 4;
            ldsB[j] = rw * 36 + (2 * g + 2 - (g & 1)) * 4;
            goff[j] = rw * HW_ + g * 8;
        }
    }
    const bf16* gbase = isK ? kbb : vbb;
    const int itstep = isK ? (32 * C_) : 32;

    // --- prologue: stage tile 0 into buffer 0 ---
    {
        short* sb = isK ? Kbuf[0] : Vbuf[0];
        #pragma unroll
        for (int j = 0; j < 3; ++j) {
            int4 r = *(const int4*)(gbase + goff[j]);
            *(int2*)(sb + ldsA[j]) = make_int2(r.x, r.y);
            *(int2*)(sb + ldsB[j]) = make_int2(r.z, r.w);
        }
    }
    __syncthreads();

    union FU { uint32_t w[4]; short8 v; };

    for (int it = 0; it < ATT_NIT; ++it) {
        int cur = it & 1;
        bool pre = (it + 1 < ATT_NIT);
        int4 r0, r1, r2;
        if (pre) {
            const bf16* g = gbase + (size_t)(it + 1) * itstep;
            r0 = *(const int4*)(g + goff[0]);
            r1 = *(const int4*)(g + goff[1]);
            r2 = *(const int4*)(g + goff[2]);
        }

        const short* Kc = Kbuf[cur];
        const short* Vc = Vbuf[cur];

        // --- K fragments (shared by both q-tiles) ---
        short8 kf[6];
        #pragma unroll
        for (int s = 0; s < 6; ++s)
            kf[s] = lds_frag(Kc + col * 100 + s * 16 + hh * 8);

        // --- S^T = K . Q^T for both tiles (independent MFMA chains) ---
        f32x16 stA = (f32x16)(0.f);
        #pragma unroll
        for (int s = 0; s < 6; ++s)
            stA = __builtin_amdgcn_mfma_f32_32x32x16_bf16(kf[s], qfA[s], stA, 0, 0, 0);
        f32x16 stB = (f32x16)(0.f);
        #pragma unroll
        for (int s = 0; s < 6; ++s)
            stB = __builtin_amdgcn_mfma_f32_32x32x16_bf16(kf[s], qfB[s], stB, 0, 0, 0);

        // --- p = exp2(s); pack straight into B-operand frags (A then B,
        //     scoped so pA's f32 temps die before pB's are built) ---
        FU f0A, f1A, f0B, f1B;
        {
            float p[16], ls = 0.f;
            #pragma unroll
            for (int i = 0; i < 16; ++i) { p[i] = fexp2(stA[i]); ls += p[i]; }
            lA += ls;
            #pragma unroll
            for (int j = 0; j < 4; ++j) {
                f0A.w[j] = pk_bf16(p[2 * j],     p[2 * j + 1]);
                f1A.w[j] = pk_bf16(p[8 + 2 * j], p[8 + 2 * j + 1]);
            }
        }
        {
            float p[16], ls = 0.f;
            #pragma unroll
            for (int i = 0; i < 16; ++i) { p[i] = fexp2(stB[i]); ls += p[i]; }
            lB += ls;
            #pragma unroll
            for (int j = 0; j < 4; ++j) {
                f0B.w[j] = pk_bf16(p[2 * j],     p[2 * j + 1]);
                f1B.w[j] = pk_bf16(p[8 + 2 * j], p[8 + 2 * j + 1]);
            }
        }

        // --- O^T += V^T . P^T : vf loaded ONCE, feeds both tiles ---
        #pragma unroll
        for (int t = 0; t < 3; ++t) {
            const short* vr = Vc + (32 * t + col) * 36 + hh * 8;
            short8 vf0 = lds_frag(vr);
            short8 vf1 = lds_frag(vr + 16);
            oaA[t] = __builtin_amdgcn_mfma_f32_32x32x16_bf16(vf0, f0A.v, oaA[t], 0, 0, 0);
            oaA[t] = __builtin_amdgcn_mfma_f32_32x32x16_bf16(vf1, f1A.v, oaA[t], 0, 0, 0);
            oaB[t] = __builtin_amdgcn_mfma_f32_32x32x16_bf16(vf0, f0B.v, oaB[t], 0, 0, 0);
            oaB[t] = __builtin_amdgcn_mfma_f32_32x32x16_bf16(vf1, f1B.v, oaB[t], 0, 0, 0);
        }

        // --- write next tile into the other buffer ---
        if (pre) {
            short* sb = isK ? Kbuf[cur ^ 1] : Vbuf[cur ^ 1];
            *(int2*)(sb + ldsA[0]) = make_int2(r0.x, r0.y);
            *(int2*)(sb + ldsB[0]) = make_int2(r0.z, r0.w);
            *(int2*)(sb + ldsA[1]) = make_int2(r1.x, r1.y);
            *(int2*)(sb + ldsB[1]) = make_int2(r1.z, r1.w);
            *(int2*)(sb + ldsA[2]) = make_int2(r2.x, r2.y);
            *(int2*)(sb + ldsB[2]) = make_int2(r2.z, r2.w);
        }
        __syncthreads();
    }

    // --- epilogue: store unnormalized partial O (bf16) and partial l ---
    {
        size_t bqA = (size_t)b * HW_ + nA;
        size_t bqB = (size_t)b * HW_ + nB;
        float ltA = lA + __shfl_xor(lA, 32, 64);
        float ltB = lB + __shfl_xor(lB, 32, 64);
        if (hh == 0) {
            pl[(size_t)ks * NT_ + bqA] = ltA;
            pl[(size_t)ks * NT_ + bqB] = ltB;
        }
        #pragma unroll
        for (int t = 0; t < 3; ++t)
            #pragma unroll
            for (int g = 0; g < 4; ++g) {
                int c0 = t * 32 + 8 * g + 4 * hh;
                uint2 pkA = make_uint2(
                    pk_bf16(oaA[t][4 * g],     oaA[t][4 * g + 1]),
                    pk_bf16(oaA[t][4 * g + 2], oaA[t][4 * g + 3]));
                *(uint2*)(pob + ((size_t)ks * NT_ + bqA) * C_ + c0) = pkA;
                uint2 pkB = make_uint2(
                    pk_bf16(oaB[t][4 * g],     oaB[t][4 * g + 1]),
                    pk_bf16(oaB[t][4 * g + 2], oaB[t][4 * g + 3]));
                *(uint2*)(pob + ((size_t)ks * NT_ + bqB) * C_ + c0) = pkB;
            }
    }
}

// ---------------------------------------------------------------------------
// Kernel 4: fused merge + output projection + residual (KSPLIT templated).
// Grid = 576 blocks x 256 thr. Coalesced merge of KS key-split partials into
// an LDS tile (stride 100 -> 2-way banks, free), then waves 0-2 MFMA GEMM.
// ---------------------------------------------------------------------------
template<int KS>
__global__ __launch_bounds__(256)
void out_kernel(const float* __restrict__ x,
                const bf16* __restrict__ pob, const float* __restrict__ pl,
                const bf16* __restrict__ wpt, const float* __restrict__ bp,
                float* __restrict__ out) {
    __shared__ short ofs[32 * 100];   // 6.4 KB merged O tile (padded stride)
    __shared__ float linv_s[32];

    int tile = blockIdx.x;            // 0..575
    int n0 = tile * 32;
    int tid = threadIdx.x;

    if (tid < 32) {
        int token = n0 + tid;
        float l = 0.f;
        #pragma unroll
        for (int ksp = 0; ksp < KS; ++ksp) l += pl[(size_t)ksp * NT_ + token];
        linv_s[tid] = 1.f / l;
    }
    __syncthreads();

    for (int pos = tid; pos < 384; pos += 256) {
        int token = pos / 12, c8 = (pos % 12) * 8;
        float acc[8] = {0.f, 0.f, 0.f, 0.f, 0.f, 0.f, 0.f, 0.f};
        #pragma unroll
        for (int ksp = 0; ksp < KS; ++ksp) {
            uint4 u = *(const uint4*)(pob + ((size_t)ksp * NT_ + n0 + token) * C_ + c8);
            acc[0] += bl(u.x); acc[1] += bh(u.x);
            acc[2] += bl(u.y); acc[3] += bh(u.y);
            acc[4] += bl(u.z); acc[5] += bh(u.z);
            acc[6] += bl(u.w); acc[7] += bh(u.w);
        }
        float inv = linv_s[token];
        short* dst = ofs + token * 100 + c8;
        *(int2*)(dst)     = make_int2(pk_bf16(acc[0] * inv, acc[1] * inv),
                                      pk_bf16(acc[2] * inv, acc[3] * inv));
        *(int2*)(dst + 4) = make_int2(pk_bf16(acc[4] * inv, acc[5] * inv),
                                      pk_bf16(acc[6] * inv, acc[7] * inv));
    }
    __syncthreads();

    int wave = tid >> 6;
    if (wave >= 3) return;
    int lane = tid & 63, col = lane & 31, hh = lane >> 5;
    int t = wave;
    int token = n0 + col;

    short8 of[6];
    #pragma unroll
    for (int s = 0; s < 6; ++s)
        of[s] = lds_frag(ofs + col * 100 + s * 16 + hh * 8);

    f32x16 acc = (f32x16)(0.f);
    const bf16* wrow = wpt + (size_t)(t * 32 + col) * C_ + hh * 8;
    #pragma unroll
    for (int s = 0; s < 6; ++s)
        acc = __builtin_amdgcn_mfma_f32_32x32x16_bf16(
                *(const short8*)(wrow + s * 16), of[s], acc, 0, 0, 0);
    #pragma unroll
    for (int g = 0; g < 4; ++g) {
        int nb = t * 32 + 8 * g + 4 * hh;
        float4 b4 = *(const float4*)(bp + nb);
        float4 xv = *(const float4*)(x + (size_t)token * C_ + nb);
        float4 rr;
        rr.x = xv.x + acc[4 * g]     + b4.x;
        rr.y = xv.y + acc[4 * g + 1] + b4.y;
        rr.z = xv.z + acc[4 * g + 2] + b4.z;
        rr.w = xv.w + acc[4 * g + 3] + b4.w;
        *(float4*)(out + (size_t)token * C_ + nb) = rr;
    }
}

// ---------------------------------------------------------------------------
extern "C" void kernel_launch(void* const* d_in, const int* in_sizes, int n_in,
                              void* d_out, int out_size, void* d_ws, size_t ws_size,
                              hipStream_t stream) {
    const float* x     = (const float*)d_in[0];
    const float* gamma = (const float*)d_in[1];
    const float* beta  = (const float*)d_in[2];
    const float* Wq    = (const float*)d_in[3];
    const float* bq    = (const float*)d_in[4];
    const float* Wk    = (const float*)d_in[5];
    const float* bk    = (const float*)d_in[6];
    const float* Wv    = (const float*)d_in[7];
    const float* bv    = (const float*)d_in[8];
    const float* Wp    = (const float*)d_in[9];
    const float* bp    = (const float*)d_in[10];
    float* out = (float*)d_out;

    char* ws = (char*)d_ws;
    const size_t TB = (size_t)NT_ * C_ * 2;   // 3.54 MB per bf16 tensor
    bf16* qb  = (bf16*)(ws);
    bf16* kb  = (bf16*)(ws + TB);
    bf16* vt  = (bf16*)(ws + 2 * TB);
    bf16* wqt = (bf16*)(ws + 3 * TB);
    bf16* wkt = (bf16*)(ws + 3 * TB + 18432);
    bf16* wvt = (bf16*)(ws + 3 * TB + 2 * 18432);
    bf16* wpt = (bf16*)(ws + 3 * TB + 3 * 18432);
    float2* stats = (float2*)(ws + 3 * TB + 4 * 18432);
    bf16*  pob = (bf16*)(ws + 3 * TB + 4 * 18432 + 512);

    hipLaunchKernelGGL(stats_prep_kernel, dim3(68), dim3(1024), 0, stream,
                       x, stats, Wq, Wk, Wv, Wp, wqt, wkt, wvt, wpt);
    hipLaunchKernelGGL(qkv_kernel, dim3(3 * 576), dim3(64), 0, stream,
                       x, stats, gamma, beta, wqt, wkt, wvt, bq, bk, bv, qb, kb, vt);

    const size_t base   = 3 * TB + 4 * 18432 + 512;
    const size_t need16 = base + (size_t)16 * NT_ * C_ * 2 + (size_t)16 * NT_ * 4;
    if (ws_size >= need16) {
        float* pl = (float*)(ws + base + (size_t)16 * NT_ * C_ * 2);
        hipLaunchKernelGGL((attn_kernel<16, 4>), dim3(16 * 72), dim3(256), 0, stream,
                           qb, kb, vt, pob, pl);
        hipLaunchKernelGGL((out_kernel<16>), dim3(576), dim3(256), 0, stream,
                           x, pob, pl, wpt, bp, out);
    } else {
        float* pl = (float*)(ws + base + (size_t)8 * NT_ * C_ * 2);
        hipLaunchKernelGGL((attn_kernel<8, 3>), dim3(8 * 72), dim3(256), 0, stream,
                           qb, kb, vt, pob, pl);
        hipLaunchKernelGGL((out_kernel<8>), dim3(576), dim3(256), 0, stream,
                           x, pob, pl, wpt, bp, out);
    }
}